// Round 4
// baseline (2421.874 us; speedup 1.0000x reference)
//
#include <hip/hip_runtime.h>
#include <cstddef>

// Problem constants (fixed by the reference).
#define N_NODES 100000
#define E_EDGES 400000
#define C_IN    128
#define C_HID   256
#define C_OUT   64

// ---------------------------------------------------------------------------
// degree: deg[dst[e]] += 1
__global__ void deg_kernel(const int* __restrict__ dst, float* __restrict__ deg, int E) {
    int e = blockIdx.x * blockDim.x + threadIdx.x;
    if (e < E) atomicAdd(&deg[dst[e]], 1.0f);
}

// deg -> 1/max(deg,1), in place
__global__ void invdeg_kernel(float* __restrict__ deg, int n) {
    int i = blockIdx.x * blockDim.x + threadIdx.x;
    if (i < n) deg[i] = 1.0f / fmaxf(deg[i], 1.0f);
}

// scatter-add feature rows: agg[dst[e]] += x[src[e]]   (C floats per row)
// C/4 threads per edge, each moves one float4.
template<int C>
__global__ void scatter_add_kernel(const int* __restrict__ src, const int* __restrict__ dst,
                                   const float* __restrict__ x, float* __restrict__ agg, int E) {
    constexpr int LANES = C / 4;            // float4 lanes per edge
    int gid = blockIdx.x * blockDim.x + threadIdx.x;
    int e = gid / LANES;
    int l = gid - e * LANES;
    if (e >= E) return;
    int s = src[e];
    int d = dst[e];
    float4 v = reinterpret_cast<const float4*>(x)[(size_t)s * LANES + l];
    float* p = agg + (size_t)d * C + l * 4;
    atomicAdd(p + 0, v.x);
    atomicAdd(p + 1, v.y);
    atomicAdd(p + 2, v.z);
    atomicAdd(p + 3, v.w);
}

// ---------------------------------------------------------------------------
// Fused SAGE GEMM:  out[M,Nout] = act( [agg*invdeg || xin] @ [Wl ; Wr] + bias )
// Logical K = 2*K_HALF.  A[r][k] = k<K_HALF ? agg[r][k]*invdeg[r] : xin[r][k-K_HALF]
// Wl, Wr are [K_HALF, Nout] row-major.
// Tiling: BM=64, BN=64, BK=16, 256 threads, 4x4 micro-tile per thread.
template<int K_HALF, bool RELU>
__global__ __launch_bounds__(256) void gemm_sage(
        const float* __restrict__ agg, const float* __restrict__ invdeg,
        const float* __restrict__ xin,
        const float* __restrict__ Wl, const float* __restrict__ Wr,
        const float* __restrict__ bias,
        float* __restrict__ out, int M, int Nout)
{
    constexpr int BM = 64, BN = 64, BK = 16;
    constexpr int K = 2 * K_HALF;
    __shared__ float As[BK][BM + 4];   // transposed A tile, stride 68 (16B-aligned rows, 2-way banks max)
    __shared__ float Bs[BK][BN];

    const int tid = threadIdx.x;
    const int tm = tid >> 4;           // 0..15 -> 4 rows each
    const int tn = tid & 15;           // 0..15 -> 4 cols each
    const int m0 = blockIdx.x * BM;
    const int n0 = blockIdx.y * BN;

    // A load mapping: one float4 per thread: row a_ml (0..63), k-offset a_kl (0,4,8,12)
    const int a_ml = tid >> 2;
    const int a_kl = (tid & 3) * 4;
    const int a_row = m0 + a_ml;
    const int a_rowc = (a_row < M) ? a_row : 0;   // clamp; unused rows never stored
    // B load mapping: one float4 per thread: k-row b_kl (0..15), n-offset b_nl
    const int b_kl = tid >> 4;
    const int b_nl = (tid & 15) * 4;

    float acc[4][4] = {};

    for (int k0 = 0; k0 < K; k0 += BK) {
        // ---- load A tile (64 x 16) with invdeg scaling / source switch
        {
            const int kg = k0 + a_kl;     // whole BK tile lives on one side (K_HALF % 16 == 0)
            const float* srcp;
            float scale;
            if (kg < K_HALF) {
                srcp  = agg + (size_t)a_rowc * K_HALF + kg;
                scale = invdeg[a_rowc];
            } else {
                srcp  = xin + (size_t)a_rowc * K_HALF + (kg - K_HALF);
                scale = 1.0f;
            }
            const float4 v = *reinterpret_cast<const float4*>(srcp);
            As[a_kl + 0][a_ml] = v.x * scale;
            As[a_kl + 1][a_ml] = v.y * scale;
            As[a_kl + 2][a_ml] = v.z * scale;
            As[a_kl + 3][a_ml] = v.w * scale;
        }
        // ---- load B tile (16 x 64)
        {
            const int kg = k0 + b_kl;
            const float* wp = (kg < K_HALF)
                ? (Wl + (size_t)kg * Nout + n0 + b_nl)
                : (Wr + (size_t)(kg - K_HALF) * Nout + n0 + b_nl);
            *reinterpret_cast<float4*>(&Bs[b_kl][b_nl]) = *reinterpret_cast<const float4*>(wp);
        }
        __syncthreads();

        #pragma unroll
        for (int kk = 0; kk < BK; ++kk) {
            const float4 a4 = *reinterpret_cast<const float4*>(&As[kk][tm * 4]);
            const float4 b4 = *reinterpret_cast<const float4*>(&Bs[kk][tn * 4]);
            const float av[4] = {a4.x, a4.y, a4.z, a4.w};
            const float bv[4] = {b4.x, b4.y, b4.z, b4.w};
            #pragma unroll
            for (int i = 0; i < 4; ++i)
                #pragma unroll
                for (int j = 0; j < 4; ++j)
                    acc[i][j] = fmaf(av[i], bv[j], acc[i][j]);
        }
        __syncthreads();
    }

    // ---- epilogue: bias (+ReLU) + float4 store
    float bvals[4];
    #pragma unroll
    for (int j = 0; j < 4; ++j) bvals[j] = bias[n0 + tn * 4 + j];

    #pragma unroll
    for (int i = 0; i < 4; ++i) {
        const int r = m0 + tm * 4 + i;
        if (r < M) {
            float4 v;
            float tmp[4];
            #pragma unroll
            for (int j = 0; j < 4; ++j) {
                float t = acc[i][j] + bvals[j];
                if (RELU) t = fmaxf(t, 0.0f);
                tmp[j] = t;
            }
            v.x = tmp[0]; v.y = tmp[1]; v.z = tmp[2]; v.w = tmp[3];
            *reinterpret_cast<float4*>(&out[(size_t)r * Nout + n0 + tn * 4]) = v;
        }
    }
}

// ---------------------------------------------------------------------------
extern "C" void kernel_launch(void* const* d_in, const int* in_sizes, int n_in,
                              void* d_out, int out_size, void* d_ws, size_t ws_size,
                              hipStream_t stream) {
    const float* x    = (const float*)d_in[0];           // [100000,128]
    const int*   eidx = (const int*)d_in[1];             // [2,400000]
    const float* W1l  = (const float*)d_in[2];           // [128,256]
    const float* b1   = (const float*)d_in[3];           // [256]
    const float* W1r  = (const float*)d_in[4];           // [128,256]
    const float* W2l  = (const float*)d_in[5];           // [256,64]
    const float* b2   = (const float*)d_in[6];           // [64]
    const float* W2r  = (const float*)d_in[7];           // [256,64]
    float* out = (float*)d_out;                          // [100000,64]

    const int* src = eidx;                               // edge_index[0]
    const int* dst = eidx + E_EDGES;                     // edge_index[1]

    // Workspace layout (floats): deg[N] | agg[N*256] (reused both layers) | h[N*256]
    float* ws  = (float*)d_ws;
    float* deg = ws;                                     // N floats (becomes invdeg in place)
    float* agg = ws + 131072;                            // N*256 floats
    float* h   = agg + (size_t)N_NODES * C_HID;          // N*256 floats

    const int M = N_NODES;
    const int E = E_EDGES;

    // ---------------- layer 1 ----------------
    hipMemsetAsync(deg, 0, (size_t)N_NODES * sizeof(float), stream);
    hipMemsetAsync(agg, 0, (size_t)N_NODES * C_IN * sizeof(float), stream);

    deg_kernel<<<(E + 255) / 256, 256, 0, stream>>>(dst, deg, E);
    {
        const int threads = E * (C_IN / 4);
        scatter_add_kernel<C_IN><<<(threads + 255) / 256, 256, 0, stream>>>(src, dst, x, agg, E);
    }
    invdeg_kernel<<<(N_NODES + 255) / 256, 256, 0, stream>>>(deg, N_NODES);

    {
        dim3 grid((M + 63) / 64, C_HID / 64);            // 1563 x 4
        gemm_sage<C_IN, true><<<grid, 256, 0, stream>>>(agg, deg, x, W1l, W1r, b1, h, M, C_HID);
    }

    // ---------------- layer 2 ----------------
    hipMemsetAsync(agg, 0, (size_t)N_NODES * C_HID * sizeof(float), stream);
    {
        const int threads = E * (C_HID / 4);
        scatter_add_kernel<C_HID><<<(threads + 255) / 256, 256, 0, stream>>>(src, dst, h, agg, E);
    }
    {
        dim3 grid((M + 63) / 64, C_OUT / 64);            // 1563 x 1
        gemm_sage<C_HID, false><<<grid, 256, 0, stream>>>(agg, deg, h, W2l, W2r, b2, out, M, C_OUT);
    }
}

// Round 5
// 737.958 us; speedup vs baseline: 3.2819x; 3.2819x over previous
//
#include <hip/hip_runtime.h>
#include <cstddef>

// Problem constants (fixed by the reference).
#define N_NODES 100000
#define E_EDGES 400000
#define C_IN    128
#define C_HID   256
#define C_OUT   64

// ---------------------------------------------------------------------------
// CSR build step 1: in-degree histogram (int atomics, 400k — cheap)
__global__ void hist_kernel(const int* __restrict__ dst, int* __restrict__ deg, int E) {
    int e = blockIdx.x * blockDim.x + threadIdx.x;
    if (e < E) atomicAdd(&deg[dst[e]], 1);
}

// CSR build step 2: exclusive prefix sum over deg[0..n) -> row_start[0..n],
// also initializes cursor = row_start. Single workgroup of 1024 threads
// (n=100k -> 98 elements/thread). ~tens of µs; revisit only if profile says so.
__global__ __launch_bounds__(1024) void scan_kernel(const int* __restrict__ deg,
                                                    int* __restrict__ row_start,
                                                    int* __restrict__ cursor, int n) {
    __shared__ int sums[1024];
    const int tid = threadIdx.x;
    const int chunk = (n + 1023) / 1024;
    const int lo = tid * chunk;
    const int hi = (lo + chunk < n) ? lo + chunk : n;
    int s = 0;
    for (int i = lo; i < hi; ++i) s += deg[i];
    sums[tid] = s;
    __syncthreads();
    // inclusive Hillis-Steele scan over 1024 partials
    for (int off = 1; off < 1024; off <<= 1) {
        int v = (tid >= off) ? sums[tid - off] : 0;
        __syncthreads();
        sums[tid] += v;
        __syncthreads();
    }
    int run = (tid == 0) ? 0 : sums[tid - 1];   // exclusive base for this chunk
    for (int i = lo; i < hi; ++i) {
        row_start[i] = run;
        cursor[i]    = run;
        run += deg[i];
    }
    if (tid == 0) row_start[n] = sums[1023];    // total = E
}

// CSR build step 3: bucket the edges (order within a bucket is irrelevant)
__global__ void fill_kernel(const int* __restrict__ src, const int* __restrict__ dst,
                            int* __restrict__ cursor, int* __restrict__ nbr, int E) {
    int e = blockIdx.x * blockDim.x + threadIdx.x;
    if (e < E) {
        int pos = atomicAdd(&cursor[dst[e]], 1);
        nbr[pos] = src[e];
    }
}

// ---------------------------------------------------------------------------
// Gather-mean: out[n] = mean over CSR neighbors of feat[nbr]  (C floats/row).
// C/4 float4-lanes per node; consecutive lanes read consecutive float4s of one
// row -> coalesced. No atomics; every output written exactly once.
template<int C>
__global__ void gather_mean_kernel(const int* __restrict__ row_start,
                                   const int* __restrict__ nbr,
                                   const float* __restrict__ feat,
                                   float* __restrict__ out, int N) {
    constexpr int LPN = C / 4;                 // float4 lanes per node
    const int gid  = blockIdx.x * blockDim.x + threadIdx.x;
    const int node = gid / LPN;
    const int lane = gid - node * LPN;
    if (node >= N) return;
    const int s = row_start[node];
    const int e = row_start[node + 1];
    float4 acc = make_float4(0.f, 0.f, 0.f, 0.f);
    const float4* f4 = reinterpret_cast<const float4*>(feat);
    for (int j = s; j < e; ++j) {
        const float4 v = f4[(size_t)nbr[j] * LPN + lane];
        acc.x += v.x; acc.y += v.y; acc.z += v.z; acc.w += v.w;
    }
    const float inv = 1.0f / (float)((e - s) > 1 ? (e - s) : 1);
    acc.x *= inv; acc.y *= inv; acc.z *= inv; acc.w *= inv;
    reinterpret_cast<float4*>(out)[(size_t)node * LPN + lane] = acc;
}

// ---------------------------------------------------------------------------
// Layer-1 GEMM: out[M,Nout] = act( [agg || xin] @ [Wl ; Wr] + bias )
// agg is already the mean (no invdeg scaling needed).
// BM=64, BN=64, BK=16, 256 threads, 4x4 micro-tile.
template<int K_HALF, bool RELU>
__global__ __launch_bounds__(256) void gemm_concat(
        const float* __restrict__ agg, const float* __restrict__ xin,
        const float* __restrict__ Wl, const float* __restrict__ Wr,
        const float* __restrict__ bias,
        float* __restrict__ out, int M, int Nout)
{
    constexpr int BM = 64, BN = 64, BK = 16;
    constexpr int K = 2 * K_HALF;
    __shared__ float As[BK][BM + 4];
    __shared__ float Bs[BK][BN];

    const int tid = threadIdx.x;
    const int tm = tid >> 4;
    const int tn = tid & 15;
    const int m0 = blockIdx.x * BM;
    const int n0 = blockIdx.y * BN;

    const int a_ml = tid >> 2;
    const int a_kl = (tid & 3) * 4;
    const int a_row = m0 + a_ml;
    const int a_rowc = (a_row < M) ? a_row : 0;
    const int b_kl = tid >> 4;
    const int b_nl = (tid & 15) * 4;

    float acc[4][4] = {};

    for (int k0 = 0; k0 < K; k0 += BK) {
        {
            const int kg = k0 + a_kl;              // BK tile entirely on one side
            const float* srcp = (kg < K_HALF)
                ? (agg + (size_t)a_rowc * K_HALF + kg)
                : (xin + (size_t)a_rowc * K_HALF + (kg - K_HALF));
            const float4 v = *reinterpret_cast<const float4*>(srcp);
            As[a_kl + 0][a_ml] = v.x;
            As[a_kl + 1][a_ml] = v.y;
            As[a_kl + 2][a_ml] = v.z;
            As[a_kl + 3][a_ml] = v.w;
        }
        {
            const int kg = k0 + b_kl;
            const float* wp = (kg < K_HALF)
                ? (Wl + (size_t)kg * Nout + n0 + b_nl)
                : (Wr + (size_t)(kg - K_HALF) * Nout + n0 + b_nl);
            *reinterpret_cast<float4*>(&Bs[b_kl][b_nl]) = *reinterpret_cast<const float4*>(wp);
        }
        __syncthreads();

        #pragma unroll
        for (int kk = 0; kk < BK; ++kk) {
            const float4 a4 = *reinterpret_cast<const float4*>(&As[kk][tm * 4]);
            const float4 b4 = *reinterpret_cast<const float4*>(&Bs[kk][tn * 4]);
            const float av[4] = {a4.x, a4.y, a4.z, a4.w};
            const float bv[4] = {b4.x, b4.y, b4.z, b4.w};
            #pragma unroll
            for (int i = 0; i < 4; ++i)
                #pragma unroll
                for (int j = 0; j < 4; ++j)
                    acc[i][j] = fmaf(av[i], bv[j], acc[i][j]);
        }
        __syncthreads();
    }

    float bvals[4];
    #pragma unroll
    for (int j = 0; j < 4; ++j) bvals[j] = bias[n0 + tn * 4 + j];

    #pragma unroll
    for (int i = 0; i < 4; ++i) {
        const int r = m0 + tm * 4 + i;
        if (r < M) {
            float4 v;
            float tmp[4];
            #pragma unroll
            for (int j = 0; j < 4; ++j) {
                float t = acc[i][j] + bvals[j];
                if (RELU) t = fmaxf(t, 0.0f);
                tmp[j] = t;
            }
            v.x = tmp[0]; v.y = tmp[1]; v.z = tmp[2]; v.w = tmp[3];
            *reinterpret_cast<float4*>(&out[(size_t)r * Nout + n0 + tn * 4]) = v;
        }
    }
}

// ---------------------------------------------------------------------------
// Layer-2 GEMMs: out[M,64] = A[M,256] @ W[256,64] (+ addrow[M,64]) (+ bias[64])
// Same tiling; N == BN == 64 so gridDim.y == 1.
template<bool ADDROW, bool BIAS>
__global__ __launch_bounds__(256) void gemm_single(
        const float* __restrict__ A, const float* __restrict__ W,
        const float* __restrict__ addrow, const float* __restrict__ bias,
        float* __restrict__ out, int M)
{
    constexpr int BM = 64, BN = 64, BK = 16, K = 256, Nout = 64;
    __shared__ float As[BK][BM + 4];
    __shared__ float Bs[BK][BN];

    const int tid = threadIdx.x;
    const int tm = tid >> 4;
    const int tn = tid & 15;
    const int m0 = blockIdx.x * BM;

    const int a_ml = tid >> 2;
    const int a_kl = (tid & 3) * 4;
    const int a_row = m0 + a_ml;
    const int a_rowc = (a_row < M) ? a_row : 0;
    const int b_kl = tid >> 4;
    const int b_nl = (tid & 15) * 4;

    float acc[4][4] = {};

    for (int k0 = 0; k0 < K; k0 += BK) {
        {
            const float4 v = *reinterpret_cast<const float4*>(
                A + (size_t)a_rowc * K + k0 + a_kl);
            As[a_kl + 0][a_ml] = v.x;
            As[a_kl + 1][a_ml] = v.y;
            As[a_kl + 2][a_ml] = v.z;
            As[a_kl + 3][a_ml] = v.w;
        }
        *reinterpret_cast<float4*>(&Bs[b_kl][b_nl]) =
            *reinterpret_cast<const float4*>(W + (size_t)(k0 + b_kl) * Nout + b_nl);
        __syncthreads();

        #pragma unroll
        for (int kk = 0; kk < BK; ++kk) {
            const float4 a4 = *reinterpret_cast<const float4*>(&As[kk][tm * 4]);
            const float4 b4 = *reinterpret_cast<const float4*>(&Bs[kk][tn * 4]);
            const float av[4] = {a4.x, a4.y, a4.z, a4.w};
            const float bv[4] = {b4.x, b4.y, b4.z, b4.w};
            #pragma unroll
            for (int i = 0; i < 4; ++i)
                #pragma unroll
                for (int j = 0; j < 4; ++j)
                    acc[i][j] = fmaf(av[i], bv[j], acc[i][j]);
        }
        __syncthreads();
    }

    float bvals[4] = {0.f, 0.f, 0.f, 0.f};
    if (BIAS) {
        #pragma unroll
        for (int j = 0; j < 4; ++j) bvals[j] = bias[tn * 4 + j];
    }

    #pragma unroll
    for (int i = 0; i < 4; ++i) {
        const int r = m0 + tm * 4 + i;
        if (r < M) {
            float4 ad = make_float4(0.f, 0.f, 0.f, 0.f);
            if (ADDROW)
                ad = *reinterpret_cast<const float4*>(addrow + (size_t)r * Nout + tn * 4);
            float4 v;
            v.x = acc[i][0] + bvals[0] + ad.x;
            v.y = acc[i][1] + bvals[1] + ad.y;
            v.z = acc[i][2] + bvals[2] + ad.z;
            v.w = acc[i][3] + bvals[3] + ad.w;
            *reinterpret_cast<float4*>(&out[(size_t)r * Nout + tn * 4]) = v;
        }
    }
}

// ---------------------------------------------------------------------------
extern "C" void kernel_launch(void* const* d_in, const int* in_sizes, int n_in,
                              void* d_out, int out_size, void* d_ws, size_t ws_size,
                              hipStream_t stream) {
    const float* x    = (const float*)d_in[0];           // [100000,128]
    const int*   eidx = (const int*)d_in[1];             // [2,400000]
    const float* W1l  = (const float*)d_in[2];           // [128,256]
    const float* b1   = (const float*)d_in[3];           // [256]
    const float* W1r  = (const float*)d_in[4];           // [128,256]
    const float* W2l  = (const float*)d_in[5];           // [256,64]
    const float* b2   = (const float*)d_in[6];           // [64]
    const float* W2r  = (const float*)d_in[7];           // [256,64]
    float* out = (float*)d_out;                          // [100000,64]

    const int* src = eidx;                               // edge_index[0]
    const int* dst = eidx + E_EDGES;                     // edge_index[1]
    const int N = N_NODES, E = E_EDGES;

    // Workspace layout:
    //   ints:   deg[N] | row_start[N+1] | cursor[N] | nbr[E]          (~2.8 MB)
    //   floats: U = agg1[N*128] (later reused as t2[N*64] + agg2[N*64]) (51.2 MB)
    //           h[N*256]                                              (102.4 MB)
    int*   deg_i     = (int*)d_ws;
    int*   row_start = deg_i + N;                        // N+1
    int*   cursor    = row_start + (N + 1);
    int*   nbr       = cursor + N;
    float* agg1      = (float*)(nbr + E);                // N*128
    float* h         = agg1 + (size_t)N * C_IN;          // N*256
    float* t2        = agg1;                             // N*64 (agg1 dead by then)
    float* agg2      = agg1 + (size_t)N * C_OUT;         // N*64

    // ---- CSR build (shared by both layers) ----
    hipMemsetAsync(deg_i, 0, (size_t)N * sizeof(int), stream);
    hist_kernel<<<(E + 255) / 256, 256, 0, stream>>>(dst, deg_i, E);
    scan_kernel<<<1, 1024, 0, stream>>>(deg_i, row_start, cursor, N);
    fill_kernel<<<(E + 255) / 256, 256, 0, stream>>>(src, dst, cursor, nbr, E);

    // ---- layer 1: agg1 = mean_nbr(x); h = relu([agg1||x] @ [W1l;W1r] + b1) ----
    gather_mean_kernel<C_IN><<<((size_t)N * (C_IN / 4) + 255) / 256, 256, 0, stream>>>(
        row_start, nbr, x, agg1, N);
    {
        dim3 grid((N + 63) / 64, C_HID / 64);
        gemm_concat<C_IN, true><<<grid, 256, 0, stream>>>(agg1, x, W1l, W1r, b1, h, N, C_HID);
    }

    // ---- layer 2 (aggregate AFTER the left GEMM: mean(h)@W2l == mean(h@W2l)) ----
    gemm_single<false, false><<<(N + 63) / 64, 256, 0, stream>>>(h, W2l, nullptr, nullptr, t2, N);
    gather_mean_kernel<C_OUT><<<((size_t)N * (C_OUT / 4) + 255) / 256, 256, 0, stream>>>(
        row_start, nbr, t2, agg2, N);
    gemm_single<true, true><<<(N + 63) / 64, 256, 0, stream>>>(h, W2r, agg2, b2, out, N);
}

// Round 9
// 498.905 us; speedup vs baseline: 4.8544x; 1.4792x over previous
//
#include <hip/hip_runtime.h>
#include <cstddef>

// Problem constants (fixed by the reference).
#define N_NODES 100000
#define E_EDGES 400000
#define C_IN    128
#define C_HID   256
#define C_OUT   64

// ---------------------------------------------------------------------------
// CSR build step 1: in-degree histogram (int atomics, 400k — cheap)
__global__ void hist_kernel(const int* __restrict__ dst, int* __restrict__ deg, int E) {
    int e = blockIdx.x * blockDim.x + threadIdx.x;
    if (e < E) atomicAdd(&deg[dst[e]], 1);
}

// 3-phase parallel exclusive scan (N=100k, tile=2048/block, 49 blocks).
// Replaces the single-WG scan_kernel that was 232 µs (0.15% occupancy).
__global__ __launch_bounds__(256) void scan_partial(const int* __restrict__ deg,
                                                    int* __restrict__ bsums, int n) {
    __shared__ int red[256];
    int base = blockIdx.x * 2048 + threadIdx.x * 8;
    int s = 0;
    #pragma unroll
    for (int i = 0; i < 8; ++i) { int idx = base + i; if (idx < n) s += deg[idx]; }
    red[threadIdx.x] = s; __syncthreads();
    for (int off = 128; off > 0; off >>= 1) {
        if (threadIdx.x < off) red[threadIdx.x] += red[threadIdx.x + off];
        __syncthreads();
    }
    if (threadIdx.x == 0) bsums[blockIdx.x] = red[0];
}

__global__ __launch_bounds__(64) void scan_bsums(int* __restrict__ bsums, int nb) {
    __shared__ int s[64];
    int t = threadIdx.x;
    s[t] = (t < nb) ? bsums[t] : 0; __syncthreads();
    for (int off = 1; off < 64; off <<= 1) {
        int v = (t >= off) ? s[t - off] : 0;
        __syncthreads();
        s[t] += v;
        __syncthreads();
    }
    if (t < nb) bsums[t] = (t == 0) ? 0 : s[t - 1];      // exclusive
}

__global__ __launch_bounds__(256) void scan_apply(const int* __restrict__ deg,
                                                  const int* __restrict__ bsums,
                                                  int* __restrict__ row_start,
                                                  int* __restrict__ cursor, int n, int E) {
    __shared__ int red[256];
    int t = threadIdx.x;
    int base = blockIdx.x * 2048 + t * 8;
    int v[8]; int s = 0;
    #pragma unroll
    for (int i = 0; i < 8; ++i) { int idx = base + i; v[i] = (idx < n) ? deg[idx] : 0; s += v[i]; }
    red[t] = s; __syncthreads();
    for (int off = 1; off < 256; off <<= 1) {            // inclusive Hillis-Steele
        int u = (t >= off) ? red[t - off] : 0;
        __syncthreads();
        red[t] += u;
        __syncthreads();
    }
    int run = bsums[blockIdx.x] + ((t == 0) ? 0 : red[t - 1]);
    #pragma unroll
    for (int i = 0; i < 8; ++i) {
        int idx = base + i;
        if (idx < n) { row_start[idx] = run; cursor[idx] = run; run += v[i]; }
    }
    if (blockIdx.x == 0 && t == 0) row_start[n] = E;
}

// CSR build step 3: bucket the edges (order within a bucket is irrelevant)
__global__ void fill_kernel(const int* __restrict__ src, const int* __restrict__ dst,
                            int* __restrict__ cursor, int* __restrict__ nbr, int E) {
    int e = blockIdx.x * blockDim.x + threadIdx.x;
    if (e < E) {
        int pos = atomicAdd(&cursor[dst[e]], 1);
        nbr[pos] = src[e];
    }
}

// ---------------------------------------------------------------------------
// Gather-mean: out[n] = mean over CSR neighbors of feat[nbr]  (C floats/row).
template<int C>
__global__ void gather_mean_kernel(const int* __restrict__ row_start,
                                   const int* __restrict__ nbr,
                                   const float* __restrict__ feat,
                                   float* __restrict__ out, int N) {
    constexpr int LPN = C / 4;                 // float4 lanes per node
    const int gid  = blockIdx.x * blockDim.x + threadIdx.x;
    const int node = gid / LPN;
    const int lane = gid - node * LPN;
    if (node >= N) return;
    const int s = row_start[node];
    const int e = row_start[node + 1];
    float4 acc = make_float4(0.f, 0.f, 0.f, 0.f);
    const float4* f4 = reinterpret_cast<const float4*>(feat);
    for (int j = s; j < e; ++j) {
        const float4 v = f4[(size_t)nbr[j] * LPN + lane];
        acc.x += v.x; acc.y += v.y; acc.z += v.z; acc.w += v.w;
    }
    const float inv = 1.0f / (float)((e - s) > 1 ? (e - s) : 1);
    acc.x *= inv; acc.y *= inv; acc.z *= inv; acc.w *= inv;
    reinterpret_cast<float4*>(out)[(size_t)node * LPN + lane] = acc;
}

// ---------------------------------------------------------------------------
// Layer-1 GEMM: out[M,Nout] = act( [agg || xin] @ [Wl ; Wr] + bias )
template<int K_HALF, bool RELU>
__global__ __launch_bounds__(256) void gemm_concat(
        const float* __restrict__ agg, const float* __restrict__ xin,
        const float* __restrict__ Wl, const float* __restrict__ Wr,
        const float* __restrict__ bias,
        float* __restrict__ out, int M, int Nout)
{
    constexpr int BM = 64, BN = 64, BK = 16;
    constexpr int K = 2 * K_HALF;
    __shared__ float As[BK][BM + 4];
    __shared__ float Bs[BK][BN];

    const int tid = threadIdx.x;
    const int tm = tid >> 4;
    const int tn = tid & 15;
    const int m0 = blockIdx.x * BM;
    const int n0 = blockIdx.y * BN;

    const int a_ml = tid >> 2;
    const int a_kl = (tid & 3) * 4;
    const int a_row = m0 + a_ml;
    const int a_rowc = (a_row < M) ? a_row : 0;
    const int b_kl = tid >> 4;
    const int b_nl = (tid & 15) * 4;

    float acc[4][4] = {};

    for (int k0 = 0; k0 < K; k0 += BK) {
        {
            const int kg = k0 + a_kl;              // BK tile entirely on one side
            const float* srcp = (kg < K_HALF)
                ? (agg + (size_t)a_rowc * K_HALF + kg)
                : (xin + (size_t)a_rowc * K_HALF + (kg - K_HALF));
            const float4 v = *reinterpret_cast<const float4*>(srcp);
            As[a_kl + 0][a_ml] = v.x;
            As[a_kl + 1][a_ml] = v.y;
            As[a_kl + 2][a_ml] = v.z;
            As[a_kl + 3][a_ml] = v.w;
        }
        {
            const int kg = k0 + b_kl;
            const float* wp = (kg < K_HALF)
                ? (Wl + (size_t)kg * Nout + n0 + b_nl)
                : (Wr + (size_t)(kg - K_HALF) * Nout + n0 + b_nl);
            *reinterpret_cast<float4*>(&Bs[b_kl][b_nl]) = *reinterpret_cast<const float4*>(wp);
        }
        __syncthreads();

        #pragma unroll
        for (int kk = 0; kk < BK; ++kk) {
            const float4 a4 = *reinterpret_cast<const float4*>(&As[kk][tm * 4]);
            const float4 b4 = *reinterpret_cast<const float4*>(&Bs[kk][tn * 4]);
            const float av[4] = {a4.x, a4.y, a4.z, a4.w};
            const float bv[4] = {b4.x, b4.y, b4.z, b4.w};
            #pragma unroll
            for (int i = 0; i < 4; ++i)
                #pragma unroll
                for (int j = 0; j < 4; ++j)
                    acc[i][j] = fmaf(av[i], bv[j], acc[i][j]);
        }
        __syncthreads();
    }

    float bvals[4];
    #pragma unroll
    for (int j = 0; j < 4; ++j) bvals[j] = bias[n0 + tn * 4 + j];

    #pragma unroll
    for (int i = 0; i < 4; ++i) {
        const int r = m0 + tm * 4 + i;
        if (r < M) {
            float4 v;
            float tmp[4];
            #pragma unroll
            for (int j = 0; j < 4; ++j) {
                float t = acc[i][j] + bvals[j];
                if (RELU) t = fmaxf(t, 0.0f);
                tmp[j] = t;
            }
            v.x = tmp[0]; v.y = tmp[1]; v.z = tmp[2]; v.w = tmp[3];
            *reinterpret_cast<float4*>(&out[(size_t)r * Nout + n0 + tn * 4]) = v;
        }
    }
}

// ---------------------------------------------------------------------------
// Layer-2 GEMMs: out[M,64] = A[M,256] @ W[256,64] (+ addrow[M,64]) (+ bias[64])
template<bool ADDROW, bool BIAS>
__global__ __launch_bounds__(256) void gemm_single(
        const float* __restrict__ A, const float* __restrict__ W,
        const float* __restrict__ addrow, const float* __restrict__ bias,
        float* __restrict__ out, int M)
{
    constexpr int BM = 64, BN = 64, BK = 16, K = 256, Nout = 64;
    __shared__ float As[BK][BM + 4];
    __shared__ float Bs[BK][BN];

    const int tid = threadIdx.x;
    const int tm = tid >> 4;
    const int tn = tid & 15;
    const int m0 = blockIdx.x * BM;

    const int a_ml = tid >> 2;
    const int a_kl = (tid & 3) * 4;
    const int a_row = m0 + a_ml;
    const int a_rowc = (a_row < M) ? a_row : 0;
    const int b_kl = tid >> 4;
    const int b_nl = (tid & 15) * 4;

    float acc[4][4] = {};

    for (int k0 = 0; k0 < K; k0 += BK) {
        {
            const float4 v = *reinterpret_cast<const float4*>(
                A + (size_t)a_rowc * K + k0 + a_kl);
            As[a_kl + 0][a_ml] = v.x;
            As[a_kl + 1][a_ml] = v.y;
            As[a_kl + 2][a_ml] = v.z;
            As[a_kl + 3][a_ml] = v.w;
        }
        *reinterpret_cast<float4*>(&Bs[b_kl][b_nl]) =
            *reinterpret_cast<const float4*>(W + (size_t)(k0 + b_kl) * Nout + b_nl);
        __syncthreads();

        #pragma unroll
        for (int kk = 0; kk < BK; ++kk) {
            const float4 a4 = *reinterpret_cast<const float4*>(&As[kk][tm * 4]);
            const float4 b4 = *reinterpret_cast<const float4*>(&Bs[kk][tn * 4]);
            const float av[4] = {a4.x, a4.y, a4.z, a4.w};
            const float bv[4] = {b4.x, b4.y, b4.z, b4.w};
            #pragma unroll
            for (int i = 0; i < 4; ++i)
                #pragma unroll
                for (int j = 0; j < 4; ++j)
                    acc[i][j] = fmaf(av[i], bv[j], acc[i][j]);
        }
        __syncthreads();
    }

    float bvals[4] = {0.f, 0.f, 0.f, 0.f};
    if (BIAS) {
        #pragma unroll
        for (int j = 0; j < 4; ++j) bvals[j] = bias[tn * 4 + j];
    }

    #pragma unroll
    for (int i = 0; i < 4; ++i) {
        const int r = m0 + tm * 4 + i;
        if (r < M) {
            float4 ad = make_float4(0.f, 0.f, 0.f, 0.f);
            if (ADDROW)
                ad = *reinterpret_cast<const float4*>(addrow + (size_t)r * Nout + tn * 4);
            float4 v;
            v.x = acc[i][0] + bvals[0] + ad.x;
            v.y = acc[i][1] + bvals[1] + ad.y;
            v.z = acc[i][2] + bvals[2] + ad.z;
            v.w = acc[i][3] + bvals[3] + ad.w;
            *reinterpret_cast<float4*>(&out[(size_t)r * Nout + tn * 4]) = v;
        }
    }
}

// ---------------------------------------------------------------------------
extern "C" void kernel_launch(void* const* d_in, const int* in_sizes, int n_in,
                              void* d_out, int out_size, void* d_ws, size_t ws_size,
                              hipStream_t stream) {
    const float* x    = (const float*)d_in[0];
    const int*   eidx = (const int*)d_in[1];
    const float* W1l  = (const float*)d_in[2];
    const float* b1   = (const float*)d_in[3];
    const float* W1r  = (const float*)d_in[4];
    const float* W2l  = (const float*)d_in[5];
    const float* b2   = (const float*)d_in[6];
    const float* W2r  = (const float*)d_in[7];
    float* out = (float*)d_out;

    const int* src = eidx;
    const int* dst = eidx + E_EDGES;
    const int N = N_NODES, E = E_EDGES;
    const int NSCAN = (N + 2047) / 2048;                 // 49 blocks

    // Workspace layout:
    //   ints:   deg[N] | row_start[N+1] | cursor[N] | nbr[E] | bsums[64]
    //   floats: agg1[N*128] (reused as t2[N*64]+agg2[N*64]) | h[N*256]
    int*   deg_i     = (int*)d_ws;
    int*   row_start = deg_i + N;
    int*   cursor    = row_start + (N + 1);
    int*   nbr       = cursor + N;
    int*   bsums     = nbr + E;                          // 64
    char*  fb        = (char*)(((size_t)(bsums + 64) + 15) & ~(size_t)15);
    float* agg1      = (float*)fb;                       // N*128
    float* h         = agg1 + (size_t)N * C_IN;          // N*256
    float* t2        = agg1;                             // N*64 (agg1 dead by then)
    float* agg2      = agg1 + (size_t)N * C_OUT;         // N*64

    // ---- CSR build (shared by both layers) ----
    hipMemsetAsync(deg_i, 0, (size_t)N * sizeof(int), stream);
    hist_kernel<<<(E + 255) / 256, 256, 0, stream>>>(dst, deg_i, E);
    scan_partial<<<NSCAN, 256, 0, stream>>>(deg_i, bsums, N);
    scan_bsums<<<1, 64, 0, stream>>>(bsums, NSCAN);
    scan_apply<<<NSCAN, 256, 0, stream>>>(deg_i, bsums, row_start, cursor, N, E);
    fill_kernel<<<(E + 255) / 256, 256, 0, stream>>>(src, dst, cursor, nbr, E);

    // ---- layer 1: agg1 = mean_nbr(x); h = relu([agg1||x] @ [W1l;W1r] + b1) ----
    gather_mean_kernel<C_IN><<<((size_t)N * (C_IN / 4) + 255) / 256, 256, 0, stream>>>(
        row_start, nbr, x, agg1, N);
    {
        dim3 grid((N + 63) / 64, C_HID / 64);
        gemm_concat<C_IN, true><<<grid, 256, 0, stream>>>(agg1, x, W1l, W1r, b1, h, N, C_HID);
    }

    // ---- layer 2 (aggregate AFTER the left GEMM: mean(h)@W2l == mean(h@W2l)) ----
    gemm_single<false, false><<<(N + 63) / 64, 256, 0, stream>>>(h, W2l, nullptr, nullptr, t2, N);
    gather_mean_kernel<C_OUT><<<((size_t)N * (C_OUT / 4) + 255) / 256, 256, 0, stream>>>(
        row_start, nbr, t2, agg2, N);
    gemm_single<true, true><<<(N + 63) / 64, 256, 0, stream>>>(h, W2r, agg2, b2, out, N);
}

// Round 10
// 392.927 us; speedup vs baseline: 6.1637x; 1.2697x over previous
//
#include <hip/hip_runtime.h>
#include <cstddef>

// Problem constants (fixed by the reference).
#define N_NODES 100000
#define E_EDGES 400000
#define C_IN    128
#define C_HID   256
#define C_OUT   64

typedef __attribute__((ext_vector_type(8))) short bf16x8;   // MFMA A/B frag (8 bf16)
typedef __attribute__((ext_vector_type(4))) float f32x4;    // MFMA C/D frag

__device__ __forceinline__ unsigned short f2bf(float f) {   // RNE f32->bf16
    union { float f; unsigned u; } x; x.f = f;
    unsigned r = x.u + 0x7fffu + ((x.u >> 16) & 1u);
    return (unsigned short)(r >> 16);
}

// ---------------------------------------------------------------------------
// CSR build step 1: in-degree histogram (int atomics, 400k — cheap)
__global__ void hist_kernel(const int* __restrict__ dst, int* __restrict__ deg, int E) {
    int e = blockIdx.x * blockDim.x + threadIdx.x;
    if (e < E) atomicAdd(&deg[dst[e]], 1);
}

// 3-phase parallel exclusive scan (N=100k, tile=2048/block, 49 blocks).
__global__ __launch_bounds__(256) void scan_partial(const int* __restrict__ deg,
                                                    int* __restrict__ bsums, int n) {
    __shared__ int red[256];
    int base = blockIdx.x * 2048 + threadIdx.x * 8;
    int s = 0;
    #pragma unroll
    for (int i = 0; i < 8; ++i) { int idx = base + i; if (idx < n) s += deg[idx]; }
    red[threadIdx.x] = s; __syncthreads();
    for (int off = 128; off > 0; off >>= 1) {
        if (threadIdx.x < off) red[threadIdx.x] += red[threadIdx.x + off];
        __syncthreads();
    }
    if (threadIdx.x == 0) bsums[blockIdx.x] = red[0];
}

__global__ __launch_bounds__(64) void scan_bsums(int* __restrict__ bsums, int nb) {
    __shared__ int s[64];
    int t = threadIdx.x;
    s[t] = (t < nb) ? bsums[t] : 0; __syncthreads();
    for (int off = 1; off < 64; off <<= 1) {
        int v = (t >= off) ? s[t - off] : 0;
        __syncthreads();
        s[t] += v;
        __syncthreads();
    }
    if (t < nb) bsums[t] = (t == 0) ? 0 : s[t - 1];      // exclusive
}

__global__ __launch_bounds__(256) void scan_apply(const int* __restrict__ deg,
                                                  const int* __restrict__ bsums,
                                                  int* __restrict__ row_start,
                                                  int* __restrict__ cursor, int n, int E) {
    __shared__ int red[256];
    int t = threadIdx.x;
    int base = blockIdx.x * 2048 + t * 8;
    int v[8]; int s = 0;
    #pragma unroll
    for (int i = 0; i < 8; ++i) { int idx = base + i; v[i] = (idx < n) ? deg[idx] : 0; s += v[i]; }
    red[t] = s; __syncthreads();
    for (int off = 1; off < 256; off <<= 1) {            // inclusive Hillis-Steele
        int u = (t >= off) ? red[t - off] : 0;
        __syncthreads();
        red[t] += u;
        __syncthreads();
    }
    int run = bsums[blockIdx.x] + ((t == 0) ? 0 : red[t - 1]);
    #pragma unroll
    for (int i = 0; i < 8; ++i) {
        int idx = base + i;
        if (idx < n) { row_start[idx] = run; cursor[idx] = run; run += v[i]; }
    }
    if (blockIdx.x == 0 && t == 0) row_start[n] = E;
}

// CSR build step 3: bucket the edges (order within a bucket is irrelevant)
__global__ void fill_kernel(const int* __restrict__ src, const int* __restrict__ dst,
                            int* __restrict__ cursor, int* __restrict__ nbr, int E) {
    int e = blockIdx.x * blockDim.x + threadIdx.x;
    if (e < E) {
        int pos = atomicAdd(&cursor[dst[e]], 1);
        nbr[pos] = src[e];
    }
}

// ---------------------------------------------------------------------------
// Gather-mean: out[n] = mean over CSR neighbors of feat[nbr]  (C floats/row).
template<int C>
__global__ void gather_mean_kernel(const int* __restrict__ row_start,
                                   const int* __restrict__ nbr,
                                   const float* __restrict__ feat,
                                   float* __restrict__ out, int N) {
    constexpr int LPN = C / 4;                 // float4 lanes per node
    const int gid  = blockIdx.x * blockDim.x + threadIdx.x;
    const int node = gid / LPN;
    const int lane = gid - node * LPN;
    if (node >= N) return;
    const int s = row_start[node];
    const int e = row_start[node + 1];
    float4 acc = make_float4(0.f, 0.f, 0.f, 0.f);
    const float4* f4 = reinterpret_cast<const float4*>(feat);
    for (int j = s; j < e; ++j) {
        const float4 v = f4[(size_t)nbr[j] * LPN + lane];
        acc.x += v.x; acc.y += v.y; acc.z += v.z; acc.w += v.w;
    }
    const float inv = 1.0f / (float)((e - s) > 1 ? (e - s) : 1);
    acc.x *= inv; acc.y *= inv; acc.z *= inv; acc.w *= inv;
    reinterpret_cast<float4*>(out)[(size_t)node * LPN + lane] = acc;
}

// ---------------------------------------------------------------------------
// Weight prep: W1T[n][k] = bf16( k<128 ? W1l[k][n] : W1r[k-128][n] ), [256][256]
__global__ void w1T_kernel(const float* __restrict__ W1l, const float* __restrict__ W1r,
                           unsigned short* __restrict__ W1T) {
    int n = blockIdx.x, k = threadIdx.x;
    float v = (k < 128) ? W1l[(size_t)k * 256 + n] : W1r[(size_t)(k - 128) * 256 + n];
    W1T[(size_t)n * 256 + k] = f2bf(v);
}

// ---------------------------------------------------------------------------
// LDS swizzle for row-major [R][32] bf16 tiles (64B rows):
// byte = row*64 + (slot16 ^ (((row>>1)&3)<<4)). Same formula write+read.
__device__ __forceinline__ int swz(int row, int slotByte) {
    return row * 64 + (slotByte ^ (((row >> 1) & 3) << 4));
}

// Layer-1 MFMA GEMM: h[M,256] = relu([Agg||X] @ W1T^T + b1).
// A sources are FP32 (gather output / original x); converted to bf16 inline
// during LDS staging. B (W1T) pre-packed bf16. Output h FP32 (layer 2 stays
// the verified fp32 path). BM=64, BN=256 (full width), BK=32, 4 waves.
// Frags (mfma_f32_16x16x32_bf16, verified m89): A/B lane l: row/col=l&15,
// k=(l>>4)*8+j; C/D: col=lane&15, row=(lane>>4)*4+reg.
__global__ __launch_bounds__(256) void gemm1_mfma(
        const float* __restrict__ Agg,           // [M,128] f32 (mean-agg)
        const float* __restrict__ X,             // [M,128] f32
        const unsigned short* __restrict__ W1T,  // [256n][256k] bf16
        const float* __restrict__ bias,          // [256]
        float* __restrict__ H,                   // [M,256] f32 out
        int M)
{
    __shared__ __align__(16) unsigned short As[64 * 32];
    __shared__ __align__(16) unsigned short Bs[256 * 32];

    const int tid  = threadIdx.x;
    const int wave = tid >> 6, lane = tid & 63;
    const int m0 = blockIdx.x * 64;

    const int a_row = tid >> 2;          // 0..63
    const int a_seg = tid & 3;           // 8 bf16 each: k-offset seg*8
    int gm = m0 + a_row; if (gm >= M) gm = M - 1;   // clamp (stores masked)

    f32x4 acc[4][4];
    #pragma unroll
    for (int m = 0; m < 4; ++m)
        #pragma unroll
        for (int n = 0; n < 4; ++n) acc[m][n] = (f32x4){0.f, 0.f, 0.f, 0.f};

    const int kb = lane >> 4;   // k-block 0..3
    const int lr = lane & 15;

    for (int k0 = 0; k0 < 256; k0 += 32) {
        // ---- stage A (64x32 bf16): load 8 f32, convert, one int4 store
        {
            const float* srcp = (k0 < 128)
                ? (Agg + (size_t)gm * 128 + k0 + a_seg * 8)
                : (X   + (size_t)gm * 128 + (k0 - 128) + a_seg * 8);
            const float4 v0 = *reinterpret_cast<const float4*>(srcp);
            const float4 v1 = *reinterpret_cast<const float4*>(srcp + 4);
            int4 w;
            w.x = (int)f2bf(v0.x) | ((int)f2bf(v0.y) << 16);
            w.y = (int)f2bf(v0.z) | ((int)f2bf(v0.w) << 16);
            w.z = (int)f2bf(v1.x) | ((int)f2bf(v1.y) << 16);
            w.w = (int)f2bf(v1.z) | ((int)f2bf(v1.w) << 16);
            *reinterpret_cast<int4*>((char*)As + swz(a_row, a_seg * 16)) = w;
        }
        // ---- stage B (256x32 bf16): four int4 copies/thread
        #pragma unroll
        for (int i = 0; i < 4; ++i) {
            int c = tid + 256 * i, row = c >> 2, slot = c & 3;
            int4 v = *reinterpret_cast<const int4*>(W1T + (size_t)row * 256 + k0 + slot * 8);
            *reinterpret_cast<int4*>((char*)Bs + swz(row, slot * 16)) = v;
        }
        __syncthreads();

        bf16x8 af[4], bfr[4];
        #pragma unroll
        for (int m = 0; m < 4; ++m)
            af[m] = *reinterpret_cast<const bf16x8*>((const char*)As + swz(m * 16 + lr, kb * 16));
        #pragma unroll
        for (int n = 0; n < 4; ++n)
            bfr[n] = *reinterpret_cast<const bf16x8*>(
                (const char*)Bs + swz(wave * 64 + n * 16 + lr, kb * 16));
        #pragma unroll
        for (int m = 0; m < 4; ++m)
            #pragma unroll
            for (int n = 0; n < 4; ++n)
                acc[m][n] = __builtin_amdgcn_mfma_f32_16x16x32_bf16(af[m], bfr[n], acc[m][n], 0, 0, 0);
        __syncthreads();
    }

    // ---- epilogue: bias + relu, f32 store
    #pragma unroll
    for (int m = 0; m < 4; ++m) {
        const int gr_base = m0 + m * 16 + (lane >> 4) * 4;
        #pragma unroll
        for (int n = 0; n < 4; ++n) {
            const int gc = wave * 64 + n * 16 + (lane & 15);
            const float b = bias[gc];
            #pragma unroll
            for (int r = 0; r < 4; ++r) {
                const int gr = gr_base + r;
                if (gr < M) {
                    float v = acc[m][n][r] + b;
                    H[(size_t)gr * 256 + gc] = fmaxf(v, 0.0f);
                }
            }
        }
    }
}

// ---------------------------------------------------------------------------
// Layer-2 GEMMs (unchanged r9 fp32 path):
// out[M,64] = A[M,256] @ W[256,64] (+ addrow[M,64]) (+ bias[64])
template<bool ADDROW, bool BIAS>
__global__ __launch_bounds__(256) void gemm_single(
        const float* __restrict__ A, const float* __restrict__ W,
        const float* __restrict__ addrow, const float* __restrict__ bias,
        float* __restrict__ out, int M)
{
    constexpr int BM = 64, BN = 64, BK = 16, K = 256, Nout = 64;
    __shared__ float As[BK][BM + 4];
    __shared__ float Bs[BK][BN];

    const int tid = threadIdx.x;
    const int tm = tid >> 4;
    const int tn = tid & 15;
    const int m0 = blockIdx.x * BM;

    const int a_ml = tid >> 2;
    const int a_kl = (tid & 3) * 4;
    const int a_row = m0 + a_ml;
    const int a_rowc = (a_row < M) ? a_row : 0;
    const int b_kl = tid >> 4;
    const int b_nl = (tid & 15) * 4;

    float acc[4][4] = {};

    for (int k0 = 0; k0 < K; k0 += BK) {
        {
            const float4 v = *reinterpret_cast<const float4*>(
                A + (size_t)a_rowc * K + k0 + a_kl);
            As[a_kl + 0][a_ml] = v.x;
            As[a_kl + 1][a_ml] = v.y;
            As[a_kl + 2][a_ml] = v.z;
            As[a_kl + 3][a_ml] = v.w;
        }
        *reinterpret_cast<float4*>(&Bs[b_kl][b_nl]) =
            *reinterpret_cast<const float4*>(W + (size_t)(k0 + b_kl) * Nout + b_nl);
        __syncthreads();

        #pragma unroll
        for (int kk = 0; kk < BK; ++kk) {
            const float4 a4 = *reinterpret_cast<const float4*>(&As[kk][tm * 4]);
            const float4 b4 = *reinterpret_cast<const float4*>(&Bs[kk][tn * 4]);
            const float av[4] = {a4.x, a4.y, a4.z, a4.w};
            const float bv[4] = {b4.x, b4.y, b4.z, b4.w};
            #pragma unroll
            for (int i = 0; i < 4; ++i)
                #pragma unroll
                for (int j = 0; j < 4; ++j)
                    acc[i][j] = fmaf(av[i], bv[j], acc[i][j]);
        }
        __syncthreads();
    }

    float bvals[4] = {0.f, 0.f, 0.f, 0.f};
    if (BIAS) {
        #pragma unroll
        for (int j = 0; j < 4; ++j) bvals[j] = bias[tn * 4 + j];
    }

    #pragma unroll
    for (int i = 0; i < 4; ++i) {
        const int r = m0 + tm * 4 + i;
        if (r < M) {
            float4 ad = make_float4(0.f, 0.f, 0.f, 0.f);
            if (ADDROW)
                ad = *reinterpret_cast<const float4*>(addrow + (size_t)r * Nout + tn * 4);
            float4 v;
            v.x = acc[i][0] + bvals[0] + ad.x;
            v.y = acc[i][1] + bvals[1] + ad.y;
            v.z = acc[i][2] + bvals[2] + ad.z;
            v.w = acc[i][3] + bvals[3] + ad.w;
            *reinterpret_cast<float4*>(&out[(size_t)r * Nout + tn * 4]) = v;
        }
    }
}

// ---------------------------------------------------------------------------
extern "C" void kernel_launch(void* const* d_in, const int* in_sizes, int n_in,
                              void* d_out, int out_size, void* d_ws, size_t ws_size,
                              hipStream_t stream) {
    const float* x    = (const float*)d_in[0];
    const int*   eidx = (const int*)d_in[1];
    const float* W1l  = (const float*)d_in[2];
    const float* b1   = (const float*)d_in[3];
    const float* W1r  = (const float*)d_in[4];
    const float* W2l  = (const float*)d_in[5];
    const float* b2   = (const float*)d_in[6];
    const float* W2r  = (const float*)d_in[7];
    float* out = (float*)d_out;

    const int* src = eidx;
    const int* dst = eidx + E_EDGES;
    const int N = N_NODES, E = E_EDGES;
    const int NSCAN = (N + 2047) / 2048;                 // 49 blocks

    // Workspace layout (~156.5 MB):
    //   ints:  deg[N] | row_start[N+1] | cursor[N] | nbr[E] | bsums[64]
    //   16B-aligned: W1T[256*256 bf16] | agg1[N*128 f32] | h[N*256 f32]
    //   t2/agg2 reuse agg1's region (dead after gemm1).
    int*   deg_i     = (int*)d_ws;
    int*   row_start = deg_i + N;
    int*   cursor    = row_start + (N + 1);
    int*   nbr       = cursor + N;
    int*   bsums     = nbr + E;                          // 64
    char*  fb        = (char*)(((size_t)(bsums + 64) + 15) & ~(size_t)15);
    unsigned short* W1T = (unsigned short*)fb;           // 256*256 (128 KB)
    float* agg1      = (float*)(fb + 256 * 256 * sizeof(unsigned short));
    float* h         = agg1 + (size_t)N * C_IN;          // N*256
    float* t2        = agg1;                             // N*64 (agg1 dead by then)
    float* agg2      = agg1 + (size_t)N * C_OUT;         // N*64

    // ---- CSR build (shared by both layers) ----
    hipMemsetAsync(deg_i, 0, (size_t)N * sizeof(int), stream);
    hist_kernel<<<(E + 255) / 256, 256, 0, stream>>>(dst, deg_i, E);
    scan_partial<<<NSCAN, 256, 0, stream>>>(deg_i, bsums, N);
    scan_bsums<<<1, 64, 0, stream>>>(bsums, NSCAN);
    scan_apply<<<NSCAN, 256, 0, stream>>>(deg_i, bsums, row_start, cursor, N, E);
    fill_kernel<<<(E + 255) / 256, 256, 0, stream>>>(src, dst, cursor, nbr, E);

    // ---- weight prep ----
    w1T_kernel<<<256, 256, 0, stream>>>(W1l, W1r, W1T);

    // ---- layer 1: agg1 = mean_nbr(x); h = relu([agg1||x] @ W1T^T + b1) ----
    gather_mean_kernel<C_IN><<<((size_t)N * (C_IN / 4) + 255) / 256, 256, 0, stream>>>(
        row_start, nbr, x, agg1, N);
    gemm1_mfma<<<(N + 63) / 64, 256, 0, stream>>>(agg1, x, W1T, b1, h, N);

    // ---- layer 2 (aggregate AFTER the left GEMM: mean(h)@W2l == mean(h@W2l)) ----
    gemm_single<false, false><<<(N + 63) / 64, 256, 0, stream>>>(h, W2l, nullptr, nullptr, t2, N);
    gather_mean_kernel<C_OUT><<<((size_t)N * (C_OUT / 4) + 255) / 256, 256, 0, stream>>>(
        row_start, nbr, t2, agg2, N);
    gemm_single<true, true><<<(N + 63) / 64, 256, 0, stream>>>(h, W2r, agg2, b2, out, N);
}

// Round 11
// 304.454 us; speedup vs baseline: 7.9548x; 1.2906x over previous
//
#include <hip/hip_runtime.h>
#include <cstddef>

// Problem constants (fixed by the reference).
#define N_NODES 100000
#define E_EDGES 400000
#define C_IN    128
#define C_HID   256
#define C_OUT   64

typedef __attribute__((ext_vector_type(8))) short bf16x8;   // MFMA A/B frag (8 bf16)
typedef __attribute__((ext_vector_type(4))) float f32x4;    // MFMA C/D frag

__device__ __forceinline__ unsigned short f2bf(float f) {   // RNE f32->bf16
    union { float f; unsigned u; } x; x.f = f;
    unsigned r = x.u + 0x7fffu + ((x.u >> 16) & 1u);
    return (unsigned short)(r >> 16);
}

// ---------------------------------------------------------------------------
// CSR build step 1: in-degree histogram (int atomics, 400k — cheap)
__global__ void hist_kernel(const int* __restrict__ dst, int* __restrict__ deg, int E) {
    int e = blockIdx.x * blockDim.x + threadIdx.x;
    if (e < E) atomicAdd(&deg[dst[e]], 1);
}

// 3-phase parallel exclusive scan (N=100k, tile=2048/block, 49 blocks).
__global__ __launch_bounds__(256) void scan_partial(const int* __restrict__ deg,
                                                    int* __restrict__ bsums, int n) {
    __shared__ int red[256];
    int base = blockIdx.x * 2048 + threadIdx.x * 8;
    int s = 0;
    #pragma unroll
    for (int i = 0; i < 8; ++i) { int idx = base + i; if (idx < n) s += deg[idx]; }
    red[threadIdx.x] = s; __syncthreads();
    for (int off = 128; off > 0; off >>= 1) {
        if (threadIdx.x < off) red[threadIdx.x] += red[threadIdx.x + off];
        __syncthreads();
    }
    if (threadIdx.x == 0) bsums[blockIdx.x] = red[0];
}

__global__ __launch_bounds__(64) void scan_bsums(int* __restrict__ bsums, int nb) {
    __shared__ int s[64];
    int t = threadIdx.x;
    s[t] = (t < nb) ? bsums[t] : 0; __syncthreads();
    for (int off = 1; off < 64; off <<= 1) {
        int v = (t >= off) ? s[t - off] : 0;
        __syncthreads();
        s[t] += v;
        __syncthreads();
    }
    if (t < nb) bsums[t] = (t == 0) ? 0 : s[t - 1];      // exclusive
}

__global__ __launch_bounds__(256) void scan_apply(const int* __restrict__ deg,
                                                  const int* __restrict__ bsums,
                                                  int* __restrict__ row_start,
                                                  int* __restrict__ cursor, int n, int E) {
    __shared__ int red[256];
    int t = threadIdx.x;
    int base = blockIdx.x * 2048 + t * 8;
    int v[8]; int s = 0;
    #pragma unroll
    for (int i = 0; i < 8; ++i) { int idx = base + i; v[i] = (idx < n) ? deg[idx] : 0; s += v[i]; }
    red[t] = s; __syncthreads();
    for (int off = 1; off < 256; off <<= 1) {            // inclusive Hillis-Steele
        int u = (t >= off) ? red[t - off] : 0;
        __syncthreads();
        red[t] += u;
        __syncthreads();
    }
    int run = bsums[blockIdx.x] + ((t == 0) ? 0 : red[t - 1]);
    #pragma unroll
    for (int i = 0; i < 8; ++i) {
        int idx = base + i;
        if (idx < n) { row_start[idx] = run; cursor[idx] = run; run += v[i]; }
    }
    if (blockIdx.x == 0 && t == 0) row_start[n] = E;
}

// CSR build step 3: bucket the edges (order within a bucket is irrelevant)
__global__ void fill_kernel(const int* __restrict__ src, const int* __restrict__ dst,
                            int* __restrict__ cursor, int* __restrict__ nbr, int E) {
    int e = blockIdx.x * blockDim.x + threadIdx.x;
    if (e < E) {
        int pos = atomicAdd(&cursor[dst[e]], 1);
        nbr[pos] = src[e];
    }
}

// ---------------------------------------------------------------------------
// Gather-mean (layer 1): out[n] = mean over CSR neighbors of feat[nbr], f32.
template<int C>
__global__ void gather_mean_kernel(const int* __restrict__ row_start,
                                   const int* __restrict__ nbr,
                                   const float* __restrict__ feat,
                                   float* __restrict__ out, int N) {
    constexpr int LPN = C / 4;                 // float4 lanes per node
    const int gid  = blockIdx.x * blockDim.x + threadIdx.x;
    const int node = gid / LPN;
    const int lane = gid - node * LPN;
    if (node >= N) return;
    const int s = row_start[node];
    const int e = row_start[node + 1];
    float4 acc = make_float4(0.f, 0.f, 0.f, 0.f);
    const float4* f4 = reinterpret_cast<const float4*>(feat);
    for (int j = s; j < e; ++j) {
        const float4 v = f4[(size_t)nbr[j] * LPN + lane];
        acc.x += v.x; acc.y += v.y; acc.z += v.z; acc.w += v.w;
    }
    const float inv = 1.0f / (float)((e - s) > 1 ? (e - s) : 1);
    acc.x *= inv; acc.y *= inv; acc.z *= inv; acc.w *= inv;
    reinterpret_cast<float4*>(out)[(size_t)node * LPN + lane] = acc;
}

// Fused gather+epilogue (layer 2): out[node] = mean_nbr(t2) + u[node] + b2.
// 16 lanes/node, float4/lane. t2 is L3-resident (25.6 MB).
__global__ void gather_out_kernel(const int* __restrict__ row_start,
                                  const int* __restrict__ nbr,
                                  const float* __restrict__ t2,   // [N,64]
                                  const float* __restrict__ u,    // [N,64]
                                  const float* __restrict__ b2,   // [64]
                                  float* __restrict__ out, int N) {
    const int gid  = blockIdx.x * blockDim.x + threadIdx.x;
    const int node = gid >> 4;
    const int lane = gid & 15;
    if (node >= N) return;
    const int s = row_start[node];
    const int e = row_start[node + 1];
    float4 acc = make_float4(0.f, 0.f, 0.f, 0.f);
    const float4* f4 = reinterpret_cast<const float4*>(t2);
    for (int j = s; j < e; ++j) {
        const float4 v = f4[(size_t)nbr[j] * 16 + lane];
        acc.x += v.x; acc.y += v.y; acc.z += v.z; acc.w += v.w;
    }
    const float inv = 1.0f / (float)((e - s) > 1 ? (e - s) : 1);
    const float4 uv = reinterpret_cast<const float4*>(u)[(size_t)node * 16 + lane];
    const float4 bv = reinterpret_cast<const float4*>(b2)[lane];
    float4 o;
    o.x = acc.x * inv + uv.x + bv.x;
    o.y = acc.y * inv + uv.y + bv.y;
    o.z = acc.z * inv + uv.z + bv.z;
    o.w = acc.w * inv + uv.w + bv.w;
    reinterpret_cast<float4*>(out)[(size_t)node * 16 + lane] = o;
}

// ---------------------------------------------------------------------------
// Weight prep.
// W1T[n][k] = bf16( k<128 ? W1l[k][n] : W1r[k-128][n] ), [256][256]
__global__ void w1T_kernel(const float* __restrict__ W1l, const float* __restrict__ W1r,
                           unsigned short* __restrict__ W1T) {
    int n = blockIdx.x, k = threadIdx.x;
    float v = (k < 128) ? W1l[(size_t)k * 256 + n] : W1r[(size_t)(k - 128) * 256 + n];
    W1T[(size_t)n * 256 + k] = f2bf(v);
}
// WT2[n][k] = bf16( n<64 ? W2l[k][n] : W2r[k][n-64] ), [128][256]
__global__ void w2T_kernel(const float* __restrict__ W2l, const float* __restrict__ W2r,
                           unsigned short* __restrict__ WT2) {
    int n = blockIdx.x, k = threadIdx.x;
    float v = (n < 64) ? W2l[(size_t)k * 64 + n] : W2r[(size_t)k * 64 + (n - 64)];
    WT2[(size_t)n * 256 + k] = f2bf(v);
}

// ---------------------------------------------------------------------------
// LDS swizzle for row-major [R][32] bf16 tiles (64B rows):
// byte = row*64 + (slot16 ^ (((row>>1)&3)<<4)). Same formula write+read.
__device__ __forceinline__ int swz(int row, int slotByte) {
    return row * 64 + (slotByte ^ (((row >> 1) & 3) << 4));
}

// Layer-1 MFMA GEMM: H[M,256] = relu([Agg||X] @ W1T^T + b1), H now bf16.
// A fp32 in (converted inline), B pre-packed bf16. BM=64, BN=256, BK=32.
__global__ __launch_bounds__(256) void gemm1_mfma(
        const float* __restrict__ Agg,           // [M,128] f32 (mean-agg)
        const float* __restrict__ X,             // [M,128] f32
        const unsigned short* __restrict__ W1T,  // [256n][256k] bf16
        const float* __restrict__ bias,          // [256]
        unsigned short* __restrict__ H,          // [M,256] bf16 out
        int M)
{
    __shared__ __align__(16) unsigned short As[64 * 32];
    __shared__ __align__(16) unsigned short Bs[256 * 32];

    const int tid  = threadIdx.x;
    const int wave = tid >> 6, lane = tid & 63;
    const int m0 = blockIdx.x * 64;

    const int a_row = tid >> 2;          // 0..63
    const int a_seg = tid & 3;           // 8 bf16 each: k-offset seg*8
    int gm = m0 + a_row; if (gm >= M) gm = M - 1;   // clamp (stores masked)

    f32x4 acc[4][4];
    #pragma unroll
    for (int m = 0; m < 4; ++m)
        #pragma unroll
        for (int n = 0; n < 4; ++n) acc[m][n] = (f32x4){0.f, 0.f, 0.f, 0.f};

    const int kb = lane >> 4;   // k-block 0..3
    const int lr = lane & 15;

    for (int k0 = 0; k0 < 256; k0 += 32) {
        // ---- stage A (64x32 bf16): load 8 f32, convert, one int4 store
        {
            const float* srcp = (k0 < 128)
                ? (Agg + (size_t)gm * 128 + k0 + a_seg * 8)
                : (X   + (size_t)gm * 128 + (k0 - 128) + a_seg * 8);
            const float4 v0 = *reinterpret_cast<const float4*>(srcp);
            const float4 v1 = *reinterpret_cast<const float4*>(srcp + 4);
            int4 w;
            w.x = (int)f2bf(v0.x) | ((int)f2bf(v0.y) << 16);
            w.y = (int)f2bf(v0.z) | ((int)f2bf(v0.w) << 16);
            w.z = (int)f2bf(v1.x) | ((int)f2bf(v1.y) << 16);
            w.w = (int)f2bf(v1.z) | ((int)f2bf(v1.w) << 16);
            *reinterpret_cast<int4*>((char*)As + swz(a_row, a_seg * 16)) = w;
        }
        // ---- stage B (256x32 bf16): four int4 copies/thread
        #pragma unroll
        for (int i = 0; i < 4; ++i) {
            int c = tid + 256 * i, row = c >> 2, slot = c & 3;
            int4 v = *reinterpret_cast<const int4*>(W1T + (size_t)row * 256 + k0 + slot * 8);
            *reinterpret_cast<int4*>((char*)Bs + swz(row, slot * 16)) = v;
        }
        __syncthreads();

        bf16x8 af[4], bfr[4];
        #pragma unroll
        for (int m = 0; m < 4; ++m)
            af[m] = *reinterpret_cast<const bf16x8*>((const char*)As + swz(m * 16 + lr, kb * 16));
        #pragma unroll
        for (int n = 0; n < 4; ++n)
            bfr[n] = *reinterpret_cast<const bf16x8*>(
                (const char*)Bs + swz(wave * 64 + n * 16 + lr, kb * 16));
        #pragma unroll
        for (int m = 0; m < 4; ++m)
            #pragma unroll
            for (int n = 0; n < 4; ++n)
                acc[m][n] = __builtin_amdgcn_mfma_f32_16x16x32_bf16(af[m], bfr[n], acc[m][n], 0, 0, 0);
        __syncthreads();
    }

    // ---- epilogue: bias + relu, bf16 store
    #pragma unroll
    for (int m = 0; m < 4; ++m) {
        const int gr_base = m0 + m * 16 + (lane >> 4) * 4;
        #pragma unroll
        for (int n = 0; n < 4; ++n) {
            const int gc = wave * 64 + n * 16 + (lane & 15);
            const float b = bias[gc];
            #pragma unroll
            for (int r = 0; r < 4; ++r) {
                const int gr = gr_base + r;
                if (gr < M) {
                    float v = acc[m][n][r] + b;
                    H[(size_t)gr * 256 + gc] = f2bf(fmaxf(v, 0.0f));
                }
            }
        }
    }
}

// Layer-2 dual MFMA GEMM: [t2 | u] = H @ WT2^T  (cols 0..63 -> t2, 64..127 -> u).
// H bf16 [M,256] read ONCE; BM=64, BN=128, BK=32, 4 waves (wave owns 32 cols).
__global__ __launch_bounds__(256) void gemm2_dual(
        const unsigned short* __restrict__ H,    // [M,256] bf16
        const unsigned short* __restrict__ WT2,  // [128n][256k] bf16
        float* __restrict__ t2,                  // [M,64] f32
        float* __restrict__ u,                   // [M,64] f32
        int M)
{
    __shared__ __align__(16) unsigned short As[64 * 32];
    __shared__ __align__(16) unsigned short Bs[128 * 32];

    const int tid  = threadIdx.x;
    const int wave = tid >> 6, lane = tid & 63;
    const int m0 = blockIdx.x * 64;

    const int a_row = tid >> 2;
    const int a_seg = tid & 3;
    int gm = m0 + a_row; if (gm >= M) gm = M - 1;

    f32x4 acc[4][2];
    #pragma unroll
    for (int m = 0; m < 4; ++m)
        #pragma unroll
        for (int n = 0; n < 2; ++n) acc[m][n] = (f32x4){0.f, 0.f, 0.f, 0.f};

    const int kb = lane >> 4;
    const int lr = lane & 15;

    for (int k0 = 0; k0 < 256; k0 += 32) {
        // ---- stage A (64x32): one int4 copy/thread from bf16 H
        {
            int4 v = *reinterpret_cast<const int4*>(H + (size_t)gm * 256 + k0 + a_seg * 8);
            *reinterpret_cast<int4*>((char*)As + swz(a_row, a_seg * 16)) = v;
        }
        // ---- stage B (128x32): two int4 copies/thread
        #pragma unroll
        for (int i = 0; i < 2; ++i) {
            int c = tid + 256 * i, row = c >> 2, slot = c & 3;
            int4 v = *reinterpret_cast<const int4*>(WT2 + (size_t)row * 256 + k0 + slot * 8);
            *reinterpret_cast<int4*>((char*)Bs + swz(row, slot * 16)) = v;
        }
        __syncthreads();

        bf16x8 af[4], bfr[2];
        #pragma unroll
        for (int m = 0; m < 4; ++m)
            af[m] = *reinterpret_cast<const bf16x8*>((const char*)As + swz(m * 16 + lr, kb * 16));
        #pragma unroll
        for (int n = 0; n < 2; ++n)
            bfr[n] = *reinterpret_cast<const bf16x8*>(
                (const char*)Bs + swz(wave * 32 + n * 16 + lr, kb * 16));
        #pragma unroll
        for (int m = 0; m < 4; ++m)
            #pragma unroll
            for (int n = 0; n < 2; ++n)
                acc[m][n] = __builtin_amdgcn_mfma_f32_16x16x32_bf16(af[m], bfr[n], acc[m][n], 0, 0, 0);
        __syncthreads();
    }

    // ---- epilogue: split columns to t2 / u, f32 stores
    #pragma unroll
    for (int m = 0; m < 4; ++m) {
        const int gr_base = m0 + m * 16 + (lane >> 4) * 4;
        #pragma unroll
        for (int n = 0; n < 2; ++n) {
            const int gc = wave * 32 + n * 16 + (lane & 15);   // 0..127
            float* dstp = (gc < 64) ? (t2 + gc) : (u + (gc - 64));
            #pragma unroll
            for (int r = 0; r < 4; ++r) {
                const int gr = gr_base + r;
                if (gr < M) dstp[(size_t)gr * 64] = acc[m][n][r];
            }
        }
    }
}

// ---------------------------------------------------------------------------
extern "C" void kernel_launch(void* const* d_in, const int* in_sizes, int n_in,
                              void* d_out, int out_size, void* d_ws, size_t ws_size,
                              hipStream_t stream) {
    const float* x    = (const float*)d_in[0];
    const int*   eidx = (const int*)d_in[1];
    const float* W1l  = (const float*)d_in[2];
    const float* b1   = (const float*)d_in[3];
    const float* W1r  = (const float*)d_in[4];
    const float* W2l  = (const float*)d_in[5];
    const float* b2   = (const float*)d_in[6];
    const float* W2r  = (const float*)d_in[7];
    float* out = (float*)d_out;

    const int* src = eidx;
    const int* dst = eidx + E_EDGES;
    const int N = N_NODES, E = E_EDGES;
    const int NSCAN = (N + 2047) / 2048;                 // 49 blocks

    // Workspace layout (~105 MB):
    //   ints:  deg[N] | row_start[N+1] | cursor[N] | nbr[E] | bsums[64]
    //   16B-aligned: W1T[256*256] | WT2[128*256] (bf16)
    //   agg1[N*128 f32] (51.2MB; reused as t2[N*64]+u[N*64] after gemm1)
    //   h[N*256 bf16] (51.2MB)
    int*   deg_i     = (int*)d_ws;
    int*   row_start = deg_i + N;
    int*   cursor    = row_start + (N + 1);
    int*   nbr       = cursor + N;
    int*   bsums     = nbr + E;                          // 64
    char*  fb        = (char*)(((size_t)(bsums + 64) + 15) & ~(size_t)15);
    unsigned short* W1T = (unsigned short*)fb;           // 256*256
    unsigned short* WT2 = W1T + 256 * 256;               // 128*256
    float* agg1      = (float*)(WT2 + 128 * 256);        // N*128 f32
    unsigned short* h = (unsigned short*)(agg1 + (size_t)N * C_IN);  // N*256 bf16
    float* t2        = agg1;                             // N*64 f32 (agg1 dead)
    float* u         = t2 + (size_t)N * C_OUT;           // N*64 f32

    // ---- CSR build (shared by both layers) ----
    hipMemsetAsync(deg_i, 0, (size_t)N * sizeof(int), stream);
    hist_kernel<<<(E + 255) / 256, 256, 0, stream>>>(dst, deg_i, E);
    scan_partial<<<NSCAN, 256, 0, stream>>>(deg_i, bsums, N);
    scan_bsums<<<1, 64, 0, stream>>>(bsums, NSCAN);
    scan_apply<<<NSCAN, 256, 0, stream>>>(deg_i, bsums, row_start, cursor, N, E);
    fill_kernel<<<(E + 255) / 256, 256, 0, stream>>>(src, dst, cursor, nbr, E);

    // ---- weight prep ----
    w1T_kernel<<<256, 256, 0, stream>>>(W1l, W1r, W1T);
    w2T_kernel<<<128, 256, 0, stream>>>(W2l, W2r, WT2);

    // ---- layer 1: agg1 = mean_nbr(x); h = relu([agg1||x] @ W1T^T + b1) ----
    gather_mean_kernel<C_IN><<<((size_t)N * (C_IN / 4) + 255) / 256, 256, 0, stream>>>(
        row_start, nbr, x, agg1, N);
    gemm1_mfma<<<(N + 63) / 64, 256, 0, stream>>>(agg1, x, W1T, b1, h, N);

    // ---- layer 2: [t2|u] = h @ [W2l|W2r]; out = mean_nbr(t2) + u + b2 ----
    gemm2_dual<<<(N + 63) / 64, 256, 0, stream>>>(h, WT2, t2, u, N);
    gather_out_kernel<<<((size_t)N * 16 + 255) / 256, 256, 0, stream>>>(
        row_start, nbr, t2, u, b2, out, N);
}

// Round 12
// 289.910 us; speedup vs baseline: 8.3539x; 1.0502x over previous
//
#include <hip/hip_runtime.h>
#include <cstddef>

// Problem constants (fixed by the reference).
#define N_NODES 100000
#define E_EDGES 400000
#define C_IN    128
#define C_HID   256
#define C_OUT   64

typedef __attribute__((ext_vector_type(8))) short bf16x8;   // MFMA A/B frag (8 bf16)
typedef __attribute__((ext_vector_type(4))) float f32x4;    // MFMA C/D frag

__device__ __forceinline__ unsigned short f2bf(float f) {   // RNE f32->bf16
    union { float f; unsigned u; } x; x.f = f;
    unsigned r = x.u + 0x7fffu + ((x.u >> 16) & 1u);
    return (unsigned short)(r >> 16);
}
__device__ __forceinline__ float bflo(int u) {   // low bf16 of packed pair -> f32
    union { int i; float f; } x; x.i = u << 16; return x.f;
}
__device__ __forceinline__ float bfhi(int u) {   // high bf16 -> f32 (no shift needed)
    union { int i; float f; } x; x.i = u & 0xffff0000; return x.f;
}

// ---------------------------------------------------------------------------
// CSR build step 1: in-degree histogram
__global__ void hist_kernel(const int* __restrict__ dst, int* __restrict__ deg, int E) {
    int e = blockIdx.x * blockDim.x + threadIdx.x;
    if (e < E) atomicAdd(&deg[dst[e]], 1);
}

// 3-phase parallel exclusive scan (N=100k, tile=2048/block, 49 blocks).
__global__ __launch_bounds__(256) void scan_partial(const int* __restrict__ deg,
                                                    int* __restrict__ bsums, int n) {
    __shared__ int red[256];
    int base = blockIdx.x * 2048 + threadIdx.x * 8;
    int s = 0;
    #pragma unroll
    for (int i = 0; i < 8; ++i) { int idx = base + i; if (idx < n) s += deg[idx]; }
    red[threadIdx.x] = s; __syncthreads();
    for (int off = 128; off > 0; off >>= 1) {
        if (threadIdx.x < off) red[threadIdx.x] += red[threadIdx.x + off];
        __syncthreads();
    }
    if (threadIdx.x == 0) bsums[blockIdx.x] = red[0];
}

__global__ __launch_bounds__(64) void scan_bsums(int* __restrict__ bsums, int nb) {
    __shared__ int s[64];
    int t = threadIdx.x;
    s[t] = (t < nb) ? bsums[t] : 0; __syncthreads();
    for (int off = 1; off < 64; off <<= 1) {
        int v = (t >= off) ? s[t - off] : 0;
        __syncthreads();
        s[t] += v;
        __syncthreads();
    }
    if (t < nb) bsums[t] = (t == 0) ? 0 : s[t - 1];      // exclusive
}

__global__ __launch_bounds__(256) void scan_apply(const int* __restrict__ deg,
                                                  const int* __restrict__ bsums,
                                                  int* __restrict__ row_start,
                                                  int* __restrict__ cursor, int n, int E) {
    __shared__ int red[256];
    int t = threadIdx.x;
    int base = blockIdx.x * 2048 + t * 8;
    int v[8]; int s = 0;
    #pragma unroll
    for (int i = 0; i < 8; ++i) { int idx = base + i; v[i] = (idx < n) ? deg[idx] : 0; s += v[i]; }
    red[t] = s; __syncthreads();
    for (int off = 1; off < 256; off <<= 1) {            // inclusive Hillis-Steele
        int u = (t >= off) ? red[t - off] : 0;
        __syncthreads();
        red[t] += u;
        __syncthreads();
    }
    int run = bsums[blockIdx.x] + ((t == 0) ? 0 : red[t - 1]);
    #pragma unroll
    for (int i = 0; i < 8; ++i) {
        int idx = base + i;
        if (idx < n) { row_start[idx] = run; cursor[idx] = run; run += v[i]; }
    }
    if (blockIdx.x == 0 && t == 0) row_start[n] = E;
}

// CSR build step 3: bucket the edges
__global__ void fill_kernel(const int* __restrict__ src, const int* __restrict__ dst,
                            int* __restrict__ cursor, int* __restrict__ nbr, int E) {
    int e = blockIdx.x * blockDim.x + threadIdx.x;
    if (e < E) {
        int pos = atomicAdd(&cursor[dst[e]], 1);
        nbr[pos] = src[e];
    }
}

// ---------------------------------------------------------------------------
// x f32 -> bf16, 8 elems/thread. n8 = N*128/8.
__global__ void cvt_x_kernel(const float* __restrict__ in,
                             unsigned short* __restrict__ out, int n8) {
    int i = blockIdx.x * blockDim.x + threadIdx.x;
    if (i >= n8) return;
    const float4* p = reinterpret_cast<const float4*>(in) + (size_t)i * 2;
    const float4 a = p[0], b = p[1];
    int4 w;
    w.x = (int)f2bf(a.x) | ((int)f2bf(a.y) << 16);
    w.y = (int)f2bf(a.z) | ((int)f2bf(a.w) << 16);
    w.z = (int)f2bf(b.x) | ((int)f2bf(b.y) << 16);
    w.w = (int)f2bf(b.z) | ((int)f2bf(b.w) << 16);
    reinterpret_cast<int4*>(out)[i] = w;
}

// ---------------------------------------------------------------------------
// Gather-mean (layer 1), bf16 in/out: agg_bf[node] = mean_nbr(x_bf).
// 16 lanes/node; each lane owns 8 bf16 (one int4) of the 128-wide row.
__global__ void gather_mean_bf16(const int* __restrict__ row_start,
                                 const int* __restrict__ nbr,
                                 const unsigned short* __restrict__ xbf,
                                 unsigned short* __restrict__ aggbf, int N) {
    const int gid  = blockIdx.x * blockDim.x + threadIdx.x;
    const int node = gid >> 4;
    const int lane = gid & 15;
    if (node >= N) return;
    const int s = row_start[node];
    const int e = row_start[node + 1];
    float acc[8] = {0.f, 0.f, 0.f, 0.f, 0.f, 0.f, 0.f, 0.f};
    const int4* f = reinterpret_cast<const int4*>(xbf);
    for (int j = s; j < e; ++j) {
        const int4 v = f[(size_t)nbr[j] * 16 + lane];
        acc[0] += bflo(v.x); acc[1] += bfhi(v.x);
        acc[2] += bflo(v.y); acc[3] += bfhi(v.y);
        acc[4] += bflo(v.z); acc[5] += bfhi(v.z);
        acc[6] += bflo(v.w); acc[7] += bfhi(v.w);
    }
    const float inv = 1.0f / (float)((e - s) > 1 ? (e - s) : 1);
    int4 w;
    w.x = (int)f2bf(acc[0] * inv) | ((int)f2bf(acc[1] * inv) << 16);
    w.y = (int)f2bf(acc[2] * inv) | ((int)f2bf(acc[3] * inv) << 16);
    w.z = (int)f2bf(acc[4] * inv) | ((int)f2bf(acc[5] * inv) << 16);
    w.w = (int)f2bf(acc[6] * inv) | ((int)f2bf(acc[7] * inv) << 16);
    reinterpret_cast<int4*>(aggbf)[(size_t)node * 16 + lane] = w;
}

// Fused gather+epilogue (layer 2): out[node] = mean_nbr(t2_bf) + u[node] + b2.
// 8 lanes/node; each lane owns 8 cols (one int4 of t2_bf, two float4 of u/out).
__global__ void gather_out_kernel(const int* __restrict__ row_start,
                                  const int* __restrict__ nbr,
                                  const unsigned short* __restrict__ t2bf,  // [N,64] bf16
                                  const float* __restrict__ u,              // [N,64] f32
                                  const float* __restrict__ b2,             // [64]
                                  float* __restrict__ out, int N) {
    const int gid  = blockIdx.x * blockDim.x + threadIdx.x;
    const int node = gid >> 3;
    const int lane = gid & 7;
    if (node >= N) return;
    const int s = row_start[node];
    const int e = row_start[node + 1];
    float acc[8] = {0.f, 0.f, 0.f, 0.f, 0.f, 0.f, 0.f, 0.f};
    const int4* f = reinterpret_cast<const int4*>(t2bf);
    for (int j = s; j < e; ++j) {
        const int4 v = f[(size_t)nbr[j] * 8 + lane];
        acc[0] += bflo(v.x); acc[1] += bfhi(v.x);
        acc[2] += bflo(v.y); acc[3] += bfhi(v.y);
        acc[4] += bflo(v.z); acc[5] += bfhi(v.z);
        acc[6] += bflo(v.w); acc[7] += bfhi(v.w);
    }
    const float inv = 1.0f / (float)((e - s) > 1 ? (e - s) : 1);
    const float4* up = reinterpret_cast<const float4*>(u) + (size_t)node * 16 + lane * 2;
    const float4 u0 = up[0], u1 = up[1];
    const float4 b0 = reinterpret_cast<const float4*>(b2)[lane * 2];
    const float4 b1 = reinterpret_cast<const float4*>(b2)[lane * 2 + 1];
    float4 o0, o1;
    o0.x = acc[0] * inv + u0.x + b0.x;
    o0.y = acc[1] * inv + u0.y + b0.y;
    o0.z = acc[2] * inv + u0.z + b0.z;
    o0.w = acc[3] * inv + u0.w + b0.w;
    o1.x = acc[4] * inv + u1.x + b1.x;
    o1.y = acc[5] * inv + u1.y + b1.y;
    o1.z = acc[6] * inv + u1.z + b1.z;
    o1.w = acc[7] * inv + u1.w + b1.w;
    float4* op = reinterpret_cast<float4*>(out) + (size_t)node * 16 + lane * 2;
    op[0] = o0; op[1] = o1;
}

// ---------------------------------------------------------------------------
// Weight prep.
// W1T[n][k] = bf16( k<128 ? W1l[k][n] : W1r[k-128][n] ), [256][256]
__global__ void w1T_kernel(const float* __restrict__ W1l, const float* __restrict__ W1r,
                           unsigned short* __restrict__ W1T) {
    int n = blockIdx.x, k = threadIdx.x;
    float v = (k < 128) ? W1l[(size_t)k * 256 + n] : W1r[(size_t)(k - 128) * 256 + n];
    W1T[(size_t)n * 256 + k] = f2bf(v);
}
// WT2[n][k] = bf16( n<64 ? W2l[k][n] : W2r[k][n-64] ), [128][256]
__global__ void w2T_kernel(const float* __restrict__ W2l, const float* __restrict__ W2r,
                           unsigned short* __restrict__ WT2) {
    int n = blockIdx.x, k = threadIdx.x;
    float v = (n < 64) ? W2l[(size_t)k * 64 + n] : W2r[(size_t)k * 64 + (n - 64)];
    WT2[(size_t)n * 256 + k] = f2bf(v);
}

// ---------------------------------------------------------------------------
// LDS swizzle for row-major [R][32] bf16 tiles (64B rows):
// byte = row*64 + (slot16 ^ (((row>>1)&3)<<4)). Same formula write+read.
__device__ __forceinline__ int swz(int row, int slotByte) {
    return row * 64 + (slotByte ^ (((row >> 1) & 3) << 4));
}

// Layer-1 MFMA GEMM: H[M,256] = relu([AggBf||XBf] @ W1T^T + b1), bf16 in/out.
// A-staging is now a pure int4 copy (both sources bf16). BM=64, BN=256, BK=32.
__global__ __launch_bounds__(256) void gemm1_mfma(
        const unsigned short* __restrict__ AggBf,  // [M,128] bf16
        const unsigned short* __restrict__ XBf,    // [M,128] bf16
        const unsigned short* __restrict__ W1T,    // [256n][256k] bf16
        const float* __restrict__ bias,            // [256]
        unsigned short* __restrict__ H,            // [M,256] bf16 out
        int M)
{
    __shared__ __align__(16) unsigned short As[64 * 32];
    __shared__ __align__(16) unsigned short Bs[256 * 32];

    const int tid  = threadIdx.x;
    const int wave = tid >> 6, lane = tid & 63;
    const int m0 = blockIdx.x * 64;

    const int a_row = tid >> 2;          // 0..63
    const int a_seg = tid & 3;           // 8 bf16 each: k-offset seg*8
    int gm = m0 + a_row; if (gm >= M) gm = M - 1;   // clamp (stores masked)

    f32x4 acc[4][4];
    #pragma unroll
    for (int m = 0; m < 4; ++m)
        #pragma unroll
        for (int n = 0; n < 4; ++n) acc[m][n] = (f32x4){0.f, 0.f, 0.f, 0.f};

    const int kb = lane >> 4;   // k-block 0..3
    const int lr = lane & 15;

    for (int k0 = 0; k0 < 256; k0 += 32) {
        // ---- stage A (64x32 bf16): one int4 copy/thread
        {
            const unsigned short* srcp = (k0 < 128)
                ? (AggBf + (size_t)gm * 128 + k0 + a_seg * 8)
                : (XBf   + (size_t)gm * 128 + (k0 - 128) + a_seg * 8);
            int4 v = *reinterpret_cast<const int4*>(srcp);
            *reinterpret_cast<int4*>((char*)As + swz(a_row, a_seg * 16)) = v;
        }
        // ---- stage B (256x32 bf16): four int4 copies/thread
        #pragma unroll
        for (int i = 0; i < 4; ++i) {
            int c = tid + 256 * i, row = c >> 2, slot = c & 3;
            int4 v = *reinterpret_cast<const int4*>(W1T + (size_t)row * 256 + k0 + slot * 8);
            *reinterpret_cast<int4*>((char*)Bs + swz(row, slot * 16)) = v;
        }
        __syncthreads();

        bf16x8 af[4], bfr[4];
        #pragma unroll
        for (int m = 0; m < 4; ++m)
            af[m] = *reinterpret_cast<const bf16x8*>((const char*)As + swz(m * 16 + lr, kb * 16));
        #pragma unroll
        for (int n = 0; n < 4; ++n)
            bfr[n] = *reinterpret_cast<const bf16x8*>(
                (const char*)Bs + swz(wave * 64 + n * 16 + lr, kb * 16));
        #pragma unroll
        for (int m = 0; m < 4; ++m)
            #pragma unroll
            for (int n = 0; n < 4; ++n)
                acc[m][n] = __builtin_amdgcn_mfma_f32_16x16x32_bf16(af[m], bfr[n], acc[m][n], 0, 0, 0);
        __syncthreads();
    }

    // ---- epilogue: bias + relu, bf16 store
    #pragma unroll
    for (int m = 0; m < 4; ++m) {
        const int gr_base = m0 + m * 16 + (lane >> 4) * 4;
        #pragma unroll
        for (int n = 0; n < 4; ++n) {
            const int gc = wave * 64 + n * 16 + (lane & 15);
            const float b = bias[gc];
            #pragma unroll
            for (int r = 0; r < 4; ++r) {
                const int gr = gr_base + r;
                if (gr < M) {
                    float v = acc[m][n][r] + b;
                    H[(size_t)gr * 256 + gc] = f2bf(fmaxf(v, 0.0f));
                }
            }
        }
    }
}

// Layer-2 dual MFMA GEMM: [t2_bf | u] = H @ WT2^T (cols 0..63 -> t2 bf16,
// 64..127 -> u f32). H read ONCE. BM=64, BN=128, BK=32, 4 waves.
__global__ __launch_bounds__(256) void gemm2_dual(
        const unsigned short* __restrict__ H,    // [M,256] bf16
        const unsigned short* __restrict__ WT2,  // [128n][256k] bf16
        unsigned short* __restrict__ t2bf,       // [M,64] bf16
        float* __restrict__ u,                   // [M,64] f32
        int M)
{
    __shared__ __align__(16) unsigned short As[64 * 32];
    __shared__ __align__(16) unsigned short Bs[128 * 32];

    const int tid  = threadIdx.x;
    const int wave = tid >> 6, lane = tid & 63;
    const int m0 = blockIdx.x * 64;

    const int a_row = tid >> 2;
    const int a_seg = tid & 3;
    int gm = m0 + a_row; if (gm >= M) gm = M - 1;

    f32x4 acc[4][2];
    #pragma unroll
    for (int m = 0; m < 4; ++m)
        #pragma unroll
        for (int n = 0; n < 2; ++n) acc[m][n] = (f32x4){0.f, 0.f, 0.f, 0.f};

    const int kb = lane >> 4;
    const int lr = lane & 15;

    for (int k0 = 0; k0 < 256; k0 += 32) {
        {
            int4 v = *reinterpret_cast<const int4*>(H + (size_t)gm * 256 + k0 + a_seg * 8);
            *reinterpret_cast<int4*>((char*)As + swz(a_row, a_seg * 16)) = v;
        }
        #pragma unroll
        for (int i = 0; i < 2; ++i) {
            int c = tid + 256 * i, row = c >> 2, slot = c & 3;
            int4 v = *reinterpret_cast<const int4*>(WT2 + (size_t)row * 256 + k0 + slot * 8);
            *reinterpret_cast<int4*>((char*)Bs + swz(row, slot * 16)) = v;
        }
        __syncthreads();

        bf16x8 af[4], bfr[2];
        #pragma unroll
        for (int m = 0; m < 4; ++m)
            af[m] = *reinterpret_cast<const bf16x8*>((const char*)As + swz(m * 16 + lr, kb * 16));
        #pragma unroll
        for (int n = 0; n < 2; ++n)
            bfr[n] = *reinterpret_cast<const bf16x8*>(
                (const char*)Bs + swz(wave * 32 + n * 16 + lr, kb * 16));
        #pragma unroll
        for (int m = 0; m < 4; ++m)
            #pragma unroll
            for (int n = 0; n < 2; ++n)
                acc[m][n] = __builtin_amdgcn_mfma_f32_16x16x32_bf16(af[m], bfr[n], acc[m][n], 0, 0, 0);
        __syncthreads();
    }

    // ---- epilogue: cols 0..63 -> t2 (bf16), 64..127 -> u (f32)
    #pragma unroll
    for (int m = 0; m < 4; ++m) {
        const int gr_base = m0 + m * 16 + (lane >> 4) * 4;
        #pragma unroll
        for (int n = 0; n < 2; ++n) {
            const int gc = wave * 32 + n * 16 + (lane & 15);   // 0..127
            #pragma unroll
            for (int r = 0; r < 4; ++r) {
                const int gr = gr_base + r;
                if (gr < M) {
                    if (gc < 64) t2bf[(size_t)gr * 64 + gc] = f2bf(acc[m][n][r]);
                    else         u[(size_t)gr * 64 + (gc - 64)] = acc[m][n][r];
                }
            }
        }
    }
}

// ---------------------------------------------------------------------------
extern "C" void kernel_launch(void* const* d_in, const int* in_sizes, int n_in,
                              void* d_out, int out_size, void* d_ws, size_t ws_size,
                              hipStream_t stream) {
    const float* x    = (const float*)d_in[0];
    const int*   eidx = (const int*)d_in[1];
    const float* W1l  = (const float*)d_in[2];
    const float* b1   = (const float*)d_in[3];
    const float* W1r  = (const float*)d_in[4];
    const float* W2l  = (const float*)d_in[5];
    const float* b2   = (const float*)d_in[6];
    const float* W2r  = (const float*)d_in[7];
    float* out = (float*)d_out;

    const int* src = eidx;
    const int* dst = eidx + E_EDGES;
    const int N = N_NODES, E = E_EDGES;
    const int NSCAN = (N + 2047) / 2048;                 // 49 blocks

    // Workspace layout (~144 MB):
    //   ints:  deg[N] | row_start[N+1] | cursor[N] | nbr[E] | bsums[64]
    //   16B-aligned bf16: W1T[256*256] | WT2[128*256] | x_bf[N*128] |
    //                     agg_bf[N*128] | h[N*256] | t2_bf[N*64]
    //   f32: u[N*64]
    int*   deg_i     = (int*)d_ws;
    int*   row_start = deg_i + N;
    int*   cursor    = row_start + (N + 1);
    int*   nbr       = cursor + N;
    int*   bsums     = nbr + E;                          // 64
    char*  fb        = (char*)(((size_t)(bsums + 64) + 15) & ~(size_t)15);
    unsigned short* W1T    = (unsigned short*)fb;               // 256*256
    unsigned short* WT2    = W1T + 256 * 256;                   // 128*256
    unsigned short* x_bf   = WT2 + 128 * 256;                   // N*128
    unsigned short* agg_bf = x_bf + (size_t)N * C_IN;           // N*128
    unsigned short* h      = agg_bf + (size_t)N * C_IN;         // N*256
    unsigned short* t2bf   = h + (size_t)N * C_HID;             // N*64
    float* u = (float*)(((size_t)(t2bf + (size_t)N * C_OUT) + 15) & ~(size_t)15);  // N*64

    // ---- input conversion (independent of CSR) ----
    cvt_x_kernel<<<(N * C_IN / 8 + 255) / 256, 256, 0, stream>>>(x, x_bf, N * C_IN / 8);
    w1T_kernel<<<256, 256, 0, stream>>>(W1l, W1r, W1T);
    w2T_kernel<<<128, 256, 0, stream>>>(W2l, W2r, WT2);

    // ---- CSR build (shared by both layers) ----
    hipMemsetAsync(deg_i, 0, (size_t)N * sizeof(int), stream);
    hist_kernel<<<(E + 255) / 256, 256, 0, stream>>>(dst, deg_i, E);
    scan_partial<<<NSCAN, 256, 0, stream>>>(deg_i, bsums, N);
    scan_bsums<<<1, 64, 0, stream>>>(bsums, NSCAN);
    scan_apply<<<NSCAN, 256, 0, stream>>>(deg_i, bsums, row_start, cursor, N, E);
    fill_kernel<<<(E + 255) / 256, 256, 0, stream>>>(src, dst, cursor, nbr, E);

    // ---- layer 1: agg_bf = mean_nbr(x_bf); h = relu([agg_bf||x_bf] @ W1T^T + b1)
    gather_mean_bf16<<<((size_t)N * 16 + 255) / 256, 256, 0, stream>>>(
        row_start, nbr, x_bf, agg_bf, N);
    gemm1_mfma<<<(N + 63) / 64, 256, 0, stream>>>(agg_bf, x_bf, W1T, b1, h, N);

    // ---- layer 2: [t2_bf|u] = h @ [W2l|W2r]; out = mean_nbr(t2_bf) + u + b2 ----
    gemm2_dual<<<(N + 63) / 64, 256, 0, stream>>>(h, WT2, t2bf, u, N);
    gather_out_kernel<<<((size_t)N * 8 + 255) / 256, 256, 0, stream>>>(
        row_start, nbr, t2bf, u, b2, out, N);
}

// Round 13
// 273.108 us; speedup vs baseline: 8.8678x; 1.0615x over previous
//
#include <hip/hip_runtime.h>
#include <cstddef>

// Problem constants (fixed by the reference).
#define N_NODES 100000
#define E_EDGES 400000
#define C_IN    128
#define C_HID   256
#define C_OUT   64

typedef __attribute__((ext_vector_type(8))) short bf16x8;   // MFMA A/B frag (8 bf16)
typedef __attribute__((ext_vector_type(4))) float f32x4;    // MFMA C/D frag

__device__ __forceinline__ unsigned short f2bf(float f) {   // RNE f32->bf16
    union { float f; unsigned u; } x; x.f = f;
    unsigned r = x.u + 0x7fffu + ((x.u >> 16) & 1u);
    return (unsigned short)(r >> 16);
}
__device__ __forceinline__ float bflo(int u) {   // low bf16 of packed pair -> f32
    union { int i; float f; } x; x.i = u << 16; return x.f;
}
__device__ __forceinline__ float bfhi(int u) {   // high bf16 -> f32 (no shift needed)
    union { int i; float f; } x; x.i = u & 0xffff0000; return x.f;
}

// ---------------------------------------------------------------------------
// CSR build step 1: in-degree histogram
__global__ void hist_kernel(const int* __restrict__ dst, int* __restrict__ deg, int E) {
    int e = blockIdx.x * blockDim.x + threadIdx.x;
    if (e < E) atomicAdd(&deg[dst[e]], 1);
}

// 3-phase parallel exclusive scan (N=100k, tile=2048/block, 49 blocks).
__global__ __launch_bounds__(256) void scan_partial(const int* __restrict__ deg,
                                                    int* __restrict__ bsums, int n) {
    __shared__ int red[256];
    int base = blockIdx.x * 2048 + threadIdx.x * 8;
    int s = 0;
    #pragma unroll
    for (int i = 0; i < 8; ++i) { int idx = base + i; if (idx < n) s += deg[idx]; }
    red[threadIdx.x] = s; __syncthreads();
    for (int off = 128; off > 0; off >>= 1) {
        if (threadIdx.x < off) red[threadIdx.x] += red[threadIdx.x + off];
        __syncthreads();
    }
    if (threadIdx.x == 0) bsums[blockIdx.x] = red[0];
}

__global__ __launch_bounds__(64) void scan_bsums(int* __restrict__ bsums, int nb) {
    __shared__ int s[64];
    int t = threadIdx.x;
    s[t] = (t < nb) ? bsums[t] : 0; __syncthreads();
    for (int off = 1; off < 64; off <<= 1) {
        int v = (t >= off) ? s[t - off] : 0;
        __syncthreads();
        s[t] += v;
        __syncthreads();
    }
    if (t < nb) bsums[t] = (t == 0) ? 0 : s[t - 1];      // exclusive
}

__global__ __launch_bounds__(256) void scan_apply(const int* __restrict__ deg,
                                                  const int* __restrict__ bsums,
                                                  int* __restrict__ row_start,
                                                  int* __restrict__ cursor, int n, int E) {
    __shared__ int red[256];
    int t = threadIdx.x;
    int base = blockIdx.x * 2048 + t * 8;
    int v[8]; int s = 0;
    #pragma unroll
    for (int i = 0; i < 8; ++i) { int idx = base + i; v[i] = (idx < n) ? deg[idx] : 0; s += v[i]; }
    red[t] = s; __syncthreads();
    for (int off = 1; off < 256; off <<= 1) {            // inclusive Hillis-Steele
        int u = (t >= off) ? red[t - off] : 0;
        __syncthreads();
        red[t] += u;
        __syncthreads();
    }
    int run = bsums[blockIdx.x] + ((t == 0) ? 0 : red[t - 1]);
    #pragma unroll
    for (int i = 0; i < 8; ++i) {
        int idx = base + i;
        if (idx < n) { row_start[idx] = run; cursor[idx] = run; run += v[i]; }
    }
    if (blockIdx.x == 0 && t == 0) row_start[n] = E;
}

// CSR build step 3: bucket the edges
__global__ void fill_kernel(const int* __restrict__ src, const int* __restrict__ dst,
                            int* __restrict__ cursor, int* __restrict__ nbr, int E) {
    int e = blockIdx.x * blockDim.x + threadIdx.x;
    if (e < E) {
        int pos = atomicAdd(&cursor[dst[e]], 1);
        nbr[pos] = src[e];
    }
}

// ---------------------------------------------------------------------------
// x f32 -> bf16, 8 elems/thread. n8 = N*128/8.
__global__ void cvt_x_kernel(const float* __restrict__ in,
                             unsigned short* __restrict__ out, int n8) {
    int i = blockIdx.x * blockDim.x + threadIdx.x;
    if (i >= n8) return;
    const float4* p = reinterpret_cast<const float4*>(in) + (size_t)i * 2;
    const float4 a = p[0], b = p[1];
    int4 w;
    w.x = (int)f2bf(a.x) | ((int)f2bf(a.y) << 16);
    w.y = (int)f2bf(a.z) | ((int)f2bf(a.w) << 16);
    w.z = (int)f2bf(b.x) | ((int)f2bf(b.y) << 16);
    w.w = (int)f2bf(b.z) | ((int)f2bf(b.w) << 16);
    reinterpret_cast<int4*>(out)[i] = w;
}

// ---------------------------------------------------------------------------
// Gather-mean (layer 1), bf16 in/out: agg_bf[node] = mean_nbr(x_bf).
__global__ void gather_mean_bf16(const int* __restrict__ row_start,
                                 const int* __restrict__ nbr,
                                 const unsigned short* __restrict__ xbf,
                                 unsigned short* __restrict__ aggbf, int N) {
    const int gid  = blockIdx.x * blockDim.x + threadIdx.x;
    const int node = gid >> 4;
    const int lane = gid & 15;
    if (node >= N) return;
    const int s = row_start[node];
    const int e = row_start[node + 1];
    float acc[8] = {0.f, 0.f, 0.f, 0.f, 0.f, 0.f, 0.f, 0.f};
    const int4* f = reinterpret_cast<const int4*>(xbf);
    for (int j = s; j < e; ++j) {
        const int4 v = f[(size_t)nbr[j] * 16 + lane];
        acc[0] += bflo(v.x); acc[1] += bfhi(v.x);
        acc[2] += bflo(v.y); acc[3] += bfhi(v.y);
        acc[4] += bflo(v.z); acc[5] += bfhi(v.z);
        acc[6] += bflo(v.w); acc[7] += bfhi(v.w);
    }
    const float inv = 1.0f / (float)((e - s) > 1 ? (e - s) : 1);
    int4 w;
    w.x = (int)f2bf(acc[0] * inv) | ((int)f2bf(acc[1] * inv) << 16);
    w.y = (int)f2bf(acc[2] * inv) | ((int)f2bf(acc[3] * inv) << 16);
    w.z = (int)f2bf(acc[4] * inv) | ((int)f2bf(acc[5] * inv) << 16);
    w.w = (int)f2bf(acc[6] * inv) | ((int)f2bf(acc[7] * inv) << 16);
    reinterpret_cast<int4*>(aggbf)[(size_t)node * 16 + lane] = w;
}

// Fused gather+epilogue (layer 2): out[node] = mean_nbr(t2_bf) + u[node] + b2.
__global__ void gather_out_kernel(const int* __restrict__ row_start,
                                  const int* __restrict__ nbr,
                                  const unsigned short* __restrict__ t2bf,  // [N,64] bf16
                                  const float* __restrict__ u,              // [N,64] f32
                                  const float* __restrict__ b2,             // [64]
                                  float* __restrict__ out, int N) {
    const int gid  = blockIdx.x * blockDim.x + threadIdx.x;
    const int node = gid >> 3;
    const int lane = gid & 7;
    if (node >= N) return;
    const int s = row_start[node];
    const int e = row_start[node + 1];
    float acc[8] = {0.f, 0.f, 0.f, 0.f, 0.f, 0.f, 0.f, 0.f};
    const int4* f = reinterpret_cast<const int4*>(t2bf);
    for (int j = s; j < e; ++j) {
        const int4 v = f[(size_t)nbr[j] * 8 + lane];
        acc[0] += bflo(v.x); acc[1] += bfhi(v.x);
        acc[2] += bflo(v.y); acc[3] += bfhi(v.y);
        acc[4] += bflo(v.z); acc[5] += bfhi(v.z);
        acc[6] += bflo(v.w); acc[7] += bfhi(v.w);
    }
    const float inv = 1.0f / (float)((e - s) > 1 ? (e - s) : 1);
    const float4* up = reinterpret_cast<const float4*>(u) + (size_t)node * 16 + lane * 2;
    const float4 u0 = up[0], u1 = up[1];
    const float4 b0 = reinterpret_cast<const float4*>(b2)[lane * 2];
    const float4 b1 = reinterpret_cast<const float4*>(b2)[lane * 2 + 1];
    float4 o0, o1;
    o0.x = acc[0] * inv + u0.x + b0.x;
    o0.y = acc[1] * inv + u0.y + b0.y;
    o0.z = acc[2] * inv + u0.z + b0.z;
    o0.w = acc[3] * inv + u0.w + b0.w;
    o1.x = acc[4] * inv + u1.x + b1.x;
    o1.y = acc[5] * inv + u1.y + b1.y;
    o1.z = acc[6] * inv + u1.z + b1.z;
    o1.w = acc[7] * inv + u1.w + b1.w;
    float4* op = reinterpret_cast<float4*>(out) + (size_t)node * 16 + lane * 2;
    op[0] = o0; op[1] = o1;
}

// ---------------------------------------------------------------------------
// Weight prep.
// W1T[n][k] = bf16( k<128 ? W1l[k][n] : W1r[k-128][n] ), [256][256]
__global__ void w1T_kernel(const float* __restrict__ W1l, const float* __restrict__ W1r,
                           unsigned short* __restrict__ W1T) {
    int n = blockIdx.x, k = threadIdx.x;
    float v = (k < 128) ? W1l[(size_t)k * 256 + n] : W1r[(size_t)(k - 128) * 256 + n];
    W1T[(size_t)n * 256 + k] = f2bf(v);
}
// WT2[n][k] = bf16( n<64 ? W2l[k][n] : W2r[k][n-64] ), [128][256]
__global__ void w2T_kernel(const float* __restrict__ W2l, const float* __restrict__ W2r,
                           unsigned short* __restrict__ WT2) {
    int n = blockIdx.x, k = threadIdx.x;
    float v = (n < 64) ? W2l[(size_t)k * 64 + n] : W2r[(size_t)k * 64 + (n - 64)];
    WT2[(size_t)n * 256 + k] = f2bf(v);
}

// ---------------------------------------------------------------------------
// LDS swizzle for row-major [R][32] bf16 staging tiles (64B rows).
__device__ __forceinline__ int swz(int row, int slotByte) {
    return row * 64 + (slotByte ^ (((row >> 1) & 3) << 4));
}
// Swizzle for the Hs tile [64][256] bf16 (512B rows): XOR 16B-slot with row&7.
// Involution; phase-2 16B reads across 8 consecutive rows hit 8 distinct slots.
__device__ __forceinline__ int hswz(int row, int byteInRow) {
    return row * 512 + (byteInRow ^ ((row & 7) << 4));
}

// ---------------------------------------------------------------------------
// FUSED both layers' GEMMs (per 64-row node tile):
//   phase 1: acc = [AggBf||XBf] @ W1T^T ; h_tile = bf16(relu(acc + b1)) -> LDS
//   phase 2: [t2_bf | u] = h_tile @ WT2^T
// Eliminates the 51.2 MB h write + 51.2 MB h re-read between kernels.
// BM=64, BK=32, 4 waves. LDS: As 4KB + Bs 16KB + Hs 32KB = 52KB (3 blocks/CU).
__global__ __launch_bounds__(256) void gemm12_fused(
        const unsigned short* __restrict__ AggBf,  // [M,128] bf16
        const unsigned short* __restrict__ XBf,    // [M,128] bf16
        const unsigned short* __restrict__ W1T,    // [256n][256k] bf16
        const float* __restrict__ b1,              // [256]
        const unsigned short* __restrict__ WT2,    // [128n][256k] bf16
        unsigned short* __restrict__ t2bf,         // [M,64] bf16
        float* __restrict__ u,                     // [M,64] f32
        int M)
{
    __shared__ __align__(16) unsigned short As[64 * 32];    // 4 KB
    __shared__ __align__(16) unsigned short Bs[256 * 32];   // 16 KB (reused phase 2)
    __shared__ __align__(16) unsigned short Hs[64 * 256];   // 32 KB h-tile

    const int tid  = threadIdx.x;
    const int wave = tid >> 6, lane = tid & 63;
    const int m0 = blockIdx.x * 64;

    const int a_row = tid >> 2;          // 0..63
    const int a_seg = tid & 3;           // 16B segment
    int gm = m0 + a_row; if (gm >= M) gm = M - 1;   // clamp (stores masked)

    const int kb = lane >> 4;            // k-block 0..3
    const int lr = lane & 15;

    // ================= phase 1: h-tile = relu([Agg||X] @ W1T^T + b1) =========
    f32x4 acc[4][4];
    #pragma unroll
    for (int m = 0; m < 4; ++m)
        #pragma unroll
        for (int n = 0; n < 4; ++n) acc[m][n] = (f32x4){0.f, 0.f, 0.f, 0.f};

    for (int k0 = 0; k0 < 256; k0 += 32) {
        {   // stage A (64x32): one int4 copy/thread
            const unsigned short* srcp = (k0 < 128)
                ? (AggBf + (size_t)gm * 128 + k0 + a_seg * 8)
                : (XBf   + (size_t)gm * 128 + (k0 - 128) + a_seg * 8);
            int4 v = *reinterpret_cast<const int4*>(srcp);
            *reinterpret_cast<int4*>((char*)As + swz(a_row, a_seg * 16)) = v;
        }
        #pragma unroll
        for (int i = 0; i < 4; ++i) {   // stage B (256x32): four int4/thread
            int c = tid + 256 * i, row = c >> 2, slot = c & 3;
            int4 v = *reinterpret_cast<const int4*>(W1T + (size_t)row * 256 + k0 + slot * 8);
            *reinterpret_cast<int4*>((char*)Bs + swz(row, slot * 16)) = v;
        }
        __syncthreads();

        bf16x8 af[4], bfr[4];
        #pragma unroll
        for (int m = 0; m < 4; ++m)
            af[m] = *reinterpret_cast<const bf16x8*>((const char*)As + swz(m * 16 + lr, kb * 16));
        #pragma unroll
        for (int n = 0; n < 4; ++n)
            bfr[n] = *reinterpret_cast<const bf16x8*>(
                (const char*)Bs + swz(wave * 64 + n * 16 + lr, kb * 16));
        #pragma unroll
        for (int m = 0; m < 4; ++m)
            #pragma unroll
            for (int n = 0; n < 4; ++n)
                acc[m][n] = __builtin_amdgcn_mfma_f32_16x16x32_bf16(af[m], bfr[n], acc[m][n], 0, 0, 0);
        __syncthreads();
    }

    // h-tile epilogue into LDS: bias + relu + bf16 (identical math to r12's H)
    #pragma unroll
    for (int m = 0; m < 4; ++m) {
        const int lrow_base = m * 16 + (lane >> 4) * 4;
        #pragma unroll
        for (int n = 0; n < 4; ++n) {
            const int lcol = wave * 64 + n * 16 + (lane & 15);
            const float b = b1[lcol];
            #pragma unroll
            for (int r = 0; r < 4; ++r) {
                const int lrow = lrow_base + r;
                float v = acc[m][n][r] + b;
                *reinterpret_cast<unsigned short*>((char*)Hs + hswz(lrow, lcol * 2)) =
                    f2bf(fmaxf(v, 0.0f));
            }
        }
    }
    __syncthreads();

    // ================= phase 2: [t2|u] = h_tile @ WT2^T ======================
    f32x4 acc2[4][2];
    #pragma unroll
    for (int m = 0; m < 4; ++m)
        #pragma unroll
        for (int n = 0; n < 2; ++n) acc2[m][n] = (f32x4){0.f, 0.f, 0.f, 0.f};

    for (int k0 = 0; k0 < 256; k0 += 32) {
        #pragma unroll
        for (int i = 0; i < 2; ++i) {   // stage B2 (128x32): two int4/thread
            int c = tid + 256 * i, row = c >> 2, slot = c & 3;
            int4 v = *reinterpret_cast<const int4*>(WT2 + (size_t)row * 256 + k0 + slot * 8);
            *reinterpret_cast<int4*>((char*)Bs + swz(row, slot * 16)) = v;
        }
        __syncthreads();

        bf16x8 af[4], bfr[2];
        #pragma unroll
        for (int m = 0; m < 4; ++m) {
            const int lrow = m * 16 + lr;
            af[m] = *reinterpret_cast<const bf16x8*>(
                (const char*)Hs + hswz(lrow, k0 * 2 + kb * 16));
        }
        #pragma unroll
        for (int n = 0; n < 2; ++n)
            bfr[n] = *reinterpret_cast<const bf16x8*>(
                (const char*)Bs + swz(wave * 32 + n * 16 + lr, kb * 16));
        #pragma unroll
        for (int m = 0; m < 4; ++m)
            #pragma unroll
            for (int n = 0; n < 2; ++n)
                acc2[m][n] = __builtin_amdgcn_mfma_f32_16x16x32_bf16(af[m], bfr[n], acc2[m][n], 0, 0, 0);
        __syncthreads();
    }

    // epilogue: cols 0..63 -> t2 (bf16), 64..127 -> u (f32); mask gr<M
    #pragma unroll
    for (int m = 0; m < 4; ++m) {
        const int gr_base = m0 + m * 16 + (lane >> 4) * 4;
        #pragma unroll
        for (int n = 0; n < 2; ++n) {
            const int gc = wave * 32 + n * 16 + (lane & 15);   // 0..127
            #pragma unroll
            for (int r = 0; r < 4; ++r) {
                const int gr = gr_base + r;
                if (gr < M) {
                    if (gc < 64) t2bf[(size_t)gr * 64 + gc] = f2bf(acc2[m][n][r]);
                    else         u[(size_t)gr * 64 + (gc - 64)] = acc2[m][n][r];
                }
            }
        }
    }
}

// ---------------------------------------------------------------------------
extern "C" void kernel_launch(void* const* d_in, const int* in_sizes, int n_in,
                              void* d_out, int out_size, void* d_ws, size_t ws_size,
                              hipStream_t stream) {
    const float* x    = (const float*)d_in[0];
    const int*   eidx = (const int*)d_in[1];
    const float* W1l  = (const float*)d_in[2];
    const float* b1   = (const float*)d_in[3];
    const float* W1r  = (const float*)d_in[4];
    const float* W2l  = (const float*)d_in[5];
    const float* b2   = (const float*)d_in[6];
    const float* W2r  = (const float*)d_in[7];
    float* out = (float*)d_out;

    const int* src = eidx;
    const int* dst = eidx + E_EDGES;
    const int N = N_NODES, E = E_EDGES;
    const int NSCAN = (N + 2047) / 2048;                 // 49 blocks

    // Workspace layout (~93 MB):
    //   ints:  deg[N] | row_start[N+1] | cursor[N] | nbr[E] | bsums[64]
    //   bf16:  W1T[256*256] | WT2[128*256] | x_bf[N*128] | agg_bf[N*128] | t2_bf[N*64]
    //   f32:   u[N*64]
    int*   deg_i     = (int*)d_ws;
    int*   row_start = deg_i + N;
    int*   cursor    = row_start + (N + 1);
    int*   nbr       = cursor + N;
    int*   bsums     = nbr + E;                          // 64
    char*  fb        = (char*)(((size_t)(bsums + 64) + 15) & ~(size_t)15);
    unsigned short* W1T    = (unsigned short*)fb;               // 256*256
    unsigned short* WT2    = W1T + 256 * 256;                   // 128*256
    unsigned short* x_bf   = WT2 + 128 * 256;                   // N*128
    unsigned short* agg_bf = x_bf + (size_t)N * C_IN;           // N*128
    unsigned short* t2bf   = agg_bf + (size_t)N * C_IN;         // N*64
    float* u = (float*)(((size_t)(t2bf + (size_t)N * C_OUT) + 15) & ~(size_t)15);  // N*64

    // ---- input conversion (independent of CSR) ----
    cvt_x_kernel<<<(N * C_IN / 8 + 255) / 256, 256, 0, stream>>>(x, x_bf, N * C_IN / 8);
    w1T_kernel<<<256, 256, 0, stream>>>(W1l, W1r, W1T);
    w2T_kernel<<<128, 256, 0, stream>>>(W2l, W2r, WT2);

    // ---- CSR build (shared by both layers) ----
    hipMemsetAsync(deg_i, 0, (size_t)N * sizeof(int), stream);
    hist_kernel<<<(E + 255) / 256, 256, 0, stream>>>(dst, deg_i, E);
    scan_partial<<<NSCAN, 256, 0, stream>>>(deg_i, bsums, N);
    scan_bsums<<<1, 64, 0, stream>>>(bsums, NSCAN);
    scan_apply<<<NSCAN, 256, 0, stream>>>(deg_i, bsums, row_start, cursor, N, E);
    fill_kernel<<<(E + 255) / 256, 256, 0, stream>>>(src, dst, cursor, nbr, E);

    // ---- layer 1 aggregation ----
    gather_mean_bf16<<<((size_t)N * 16 + 255) / 256, 256, 0, stream>>>(
        row_start, nbr, x_bf, agg_bf, N);

    // ---- fused GEMMs: h-tile in LDS; [t2_bf|u] out ----
    gemm12_fused<<<(N + 63) / 64, 256, 0, stream>>>(
        agg_bf, x_bf, W1T, b1, WT2, t2bf, u, N);

    // ---- final: out = mean_nbr(t2_bf) + u + b2 ----
    gather_out_kernel<<<((size_t)N * 8 + 255) / 256, 256, 0, stream>>>(
        row_start, nbr, t2bf, u, b2, out, N);
}

// Round 14
// 261.670 us; speedup vs baseline: 9.2555x; 1.0437x over previous
//
#include <hip/hip_runtime.h>
#include <cstddef>

// Problem constants (fixed by the reference).
#define N_NODES 100000
#define E_EDGES 400000
#define C_IN    128
#define C_HID   256
#define C_OUT   64

typedef __attribute__((ext_vector_type(8))) short bf16x8;   // MFMA A/B frag (8 bf16)
typedef __attribute__((ext_vector_type(4))) float f32x4;    // MFMA C/D frag

__device__ __forceinline__ unsigned short f2bf(float f) {   // RNE f32->bf16
    union { float f; unsigned u; } x; x.f = f;
    unsigned r = x.u + 0x7fffu + ((x.u >> 16) & 1u);
    return (unsigned short)(r >> 16);
}
__device__ __forceinline__ float bflo(int u) {   // low bf16 of packed pair -> f32
    union { int i; float f; } x; x.i = u << 16; return x.f;
}
__device__ __forceinline__ float bfhi(int u) {   // high bf16 -> f32 (no shift needed)
    union { int i; float f; } x; x.i = u & 0xffff0000; return x.f;
}

// Async global->LDS, 16B per lane. LDS dest = wave-uniform base + lane*16
// (m104); swizzling must therefore be applied to the SOURCE address (m173).
__device__ __forceinline__ void gll16(const void* g, void* l) {
    __builtin_amdgcn_global_load_lds(
        (const __attribute__((address_space(1))) void*)g,
        (__attribute__((address_space(3))) void*)l, 16, 0, 0);
}

// ---------------------------------------------------------------------------
// CSR build step 1: in-degree histogram
__global__ void hist_kernel(const int* __restrict__ dst, int* __restrict__ deg, int E) {
    int e = blockIdx.x * blockDim.x + threadIdx.x;
    if (e < E) atomicAdd(&deg[dst[e]], 1);
}

// 3-phase parallel exclusive scan (N=100k, tile=2048/block, 49 blocks).
__global__ __launch_bounds__(256) void scan_partial(const int* __restrict__ deg,
                                                    int* __restrict__ bsums, int n) {
    __shared__ int red[256];
    int base = blockIdx.x * 2048 + threadIdx.x * 8;
    int s = 0;
    #pragma unroll
    for (int i = 0; i < 8; ++i) { int idx = base + i; if (idx < n) s += deg[idx]; }
    red[threadIdx.x] = s; __syncthreads();
    for (int off = 128; off > 0; off >>= 1) {
        if (threadIdx.x < off) red[threadIdx.x] += red[threadIdx.x + off];
        __syncthreads();
    }
    if (threadIdx.x == 0) bsums[blockIdx.x] = red[0];
}

__global__ __launch_bounds__(64) void scan_bsums(int* __restrict__ bsums, int nb) {
    __shared__ int s[64];
    int t = threadIdx.x;
    s[t] = (t < nb) ? bsums[t] : 0; __syncthreads();
    for (int off = 1; off < 64; off <<= 1) {
        int v = (t >= off) ? s[t - off] : 0;
        __syncthreads();
        s[t] += v;
        __syncthreads();
    }
    if (t < nb) bsums[t] = (t == 0) ? 0 : s[t - 1];      // exclusive
}

__global__ __launch_bounds__(256) void scan_apply(const int* __restrict__ deg,
                                                  const int* __restrict__ bsums,
                                                  int* __restrict__ row_start,
                                                  int* __restrict__ cursor, int n, int E) {
    __shared__ int red[256];
    int t = threadIdx.x;
    int base = blockIdx.x * 2048 + t * 8;
    int v[8]; int s = 0;
    #pragma unroll
    for (int i = 0; i < 8; ++i) { int idx = base + i; v[i] = (idx < n) ? deg[idx] : 0; s += v[i]; }
    red[t] = s; __syncthreads();
    for (int off = 1; off < 256; off <<= 1) {            // inclusive Hillis-Steele
        int u = (t >= off) ? red[t - off] : 0;
        __syncthreads();
        red[t] += u;
        __syncthreads();
    }
    int run = bsums[blockIdx.x] + ((t == 0) ? 0 : red[t - 1]);
    #pragma unroll
    for (int i = 0; i < 8; ++i) {
        int idx = base + i;
        if (idx < n) { row_start[idx] = run; cursor[idx] = run; run += v[i]; }
    }
    if (blockIdx.x == 0 && t == 0) row_start[n] = E;
}

// CSR build step 3: bucket the edges
__global__ void fill_kernel(const int* __restrict__ src, const int* __restrict__ dst,
                            int* __restrict__ cursor, int* __restrict__ nbr, int E) {
    int e = blockIdx.x * blockDim.x + threadIdx.x;
    if (e < E) {
        int pos = atomicAdd(&cursor[dst[e]], 1);
        nbr[pos] = src[e];
    }
}

// ---------------------------------------------------------------------------
// x f32 -> bf16, 8 elems/thread. n8 = N*128/8.
__global__ void cvt_x_kernel(const float* __restrict__ in,
                             unsigned short* __restrict__ out, int n8) {
    int i = blockIdx.x * blockDim.x + threadIdx.x;
    if (i >= n8) return;
    const float4* p = reinterpret_cast<const float4*>(in) + (size_t)i * 2;
    const float4 a = p[0], b = p[1];
    int4 w;
    w.x = (int)f2bf(a.x) | ((int)f2bf(a.y) << 16);
    w.y = (int)f2bf(a.z) | ((int)f2bf(a.w) << 16);
    w.z = (int)f2bf(b.x) | ((int)f2bf(b.y) << 16);
    w.w = (int)f2bf(b.z) | ((int)f2bf(b.w) << 16);
    reinterpret_cast<int4*>(out)[i] = w;
}

// ---------------------------------------------------------------------------
// Gather-mean (layer 1), bf16 in/out: agg_bf[node] = mean_nbr(x_bf).
__global__ void gather_mean_bf16(const int* __restrict__ row_start,
                                 const int* __restrict__ nbr,
                                 const unsigned short* __restrict__ xbf,
                                 unsigned short* __restrict__ aggbf, int N) {
    const int gid  = blockIdx.x * blockDim.x + threadIdx.x;
    const int node = gid >> 4;
    const int lane = gid & 15;
    if (node >= N) return;
    const int s = row_start[node];
    const int e = row_start[node + 1];
    float acc[8] = {0.f, 0.f, 0.f, 0.f, 0.f, 0.f, 0.f, 0.f};
    const int4* f = reinterpret_cast<const int4*>(xbf);
    for (int j = s; j < e; ++j) {
        const int4 v = f[(size_t)nbr[j] * 16 + lane];
        acc[0] += bflo(v.x); acc[1] += bfhi(v.x);
        acc[2] += bflo(v.y); acc[3] += bfhi(v.y);
        acc[4] += bflo(v.z); acc[5] += bfhi(v.z);
        acc[6] += bflo(v.w); acc[7] += bfhi(v.w);
    }
    const float inv = 1.0f / (float)((e - s) > 1 ? (e - s) : 1);
    int4 w;
    w.x = (int)f2bf(acc[0] * inv) | ((int)f2bf(acc[1] * inv) << 16);
    w.y = (int)f2bf(acc[2] * inv) | ((int)f2bf(acc[3] * inv) << 16);
    w.z = (int)f2bf(acc[4] * inv) | ((int)f2bf(acc[5] * inv) << 16);
    w.w = (int)f2bf(acc[6] * inv) | ((int)f2bf(acc[7] * inv) << 16);
    reinterpret_cast<int4*>(aggbf)[(size_t)node * 16 + lane] = w;
}

// Fused gather+epilogue (layer 2): out[node] = mean_nbr(t2_bf) + u[node] + b2.
__global__ void gather_out_kernel(const int* __restrict__ row_start,
                                  const int* __restrict__ nbr,
                                  const unsigned short* __restrict__ t2bf,  // [N,64] bf16
                                  const float* __restrict__ u,              // [N,64] f32
                                  const float* __restrict__ b2,             // [64]
                                  float* __restrict__ out, int N) {
    const int gid  = blockIdx.x * blockDim.x + threadIdx.x;
    const int node = gid >> 3;
    const int lane = gid & 7;
    if (node >= N) return;
    const int s = row_start[node];
    const int e = row_start[node + 1];
    float acc[8] = {0.f, 0.f, 0.f, 0.f, 0.f, 0.f, 0.f, 0.f};
    const int4* f = reinterpret_cast<const int4*>(t2bf);
    for (int j = s; j < e; ++j) {
        const int4 v = f[(size_t)nbr[j] * 8 + lane];
        acc[0] += bflo(v.x); acc[1] += bfhi(v.x);
        acc[2] += bflo(v.y); acc[3] += bfhi(v.y);
        acc[4] += bflo(v.z); acc[5] += bfhi(v.z);
        acc[6] += bflo(v.w); acc[7] += bfhi(v.w);
    }
    const float inv = 1.0f / (float)((e - s) > 1 ? (e - s) : 1);
    const float4* up = reinterpret_cast<const float4*>(u) + (size_t)node * 16 + lane * 2;
    const float4 u0 = up[0], u1 = up[1];
    const float4 b0 = reinterpret_cast<const float4*>(b2)[lane * 2];
    const float4 b1 = reinterpret_cast<const float4*>(b2)[lane * 2 + 1];
    float4 o0, o1;
    o0.x = acc[0] * inv + u0.x + b0.x;
    o0.y = acc[1] * inv + u0.y + b0.y;
    o0.z = acc[2] * inv + u0.z + b0.z;
    o0.w = acc[3] * inv + u0.w + b0.w;
    o1.x = acc[4] * inv + u1.x + b1.x;
    o1.y = acc[5] * inv + u1.y + b1.y;
    o1.z = acc[6] * inv + u1.z + b1.z;
    o1.w = acc[7] * inv + u1.w + b1.w;
    float4* op = reinterpret_cast<float4*>(out) + (size_t)node * 16 + lane * 2;
    op[0] = o0; op[1] = o1;
}

// ---------------------------------------------------------------------------
// Weight prep.
// W1T[n][k] = bf16( k<128 ? W1l[k][n] : W1r[k-128][n] ), [256][256]
__global__ void w1T_kernel(const float* __restrict__ W1l, const float* __restrict__ W1r,
                           unsigned short* __restrict__ W1T) {
    int n = blockIdx.x, k = threadIdx.x;
    float v = (k < 128) ? W1l[(size_t)k * 256 + n] : W1r[(size_t)(k - 128) * 256 + n];
    W1T[(size_t)n * 256 + k] = f2bf(v);
}
// WT2[n][k] = bf16( n<64 ? W2l[k][n] : W2r[k][n-64] ), [128][256]
__global__ void w2T_kernel(const float* __restrict__ W2l, const float* __restrict__ W2r,
                           unsigned short* __restrict__ WT2) {
    int n = blockIdx.x, k = threadIdx.x;
    float v = (n < 64) ? W2l[(size_t)k * 64 + n] : W2r[(size_t)k * 64 + (n - 64)];
    WT2[(size_t)n * 256 + k] = f2bf(v);
}

// ---------------------------------------------------------------------------
// LDS swizzle for row-major [R][32] bf16 staging tiles (64B rows). With GLL
// the LDS write is linear; lane l pre-swizzles its SOURCE k-block instead:
// kbsrc = (l&3) ^ ((row>>1)&3)  (same involution, applied to the read addr).
__device__ __forceinline__ int swz(int row, int slotByte) {
    return row * 64 + (slotByte ^ (((row >> 1) & 3) << 4));
}
// Swizzle for the Hs tile [64][256] bf16 (512B rows): XOR 16B-slot with row&7.
__device__ __forceinline__ int hswz(int row, int byteInRow) {
    return row * 512 + (byteInRow ^ ((row & 7) << 4));
}

// ---------------------------------------------------------------------------
// FUSED both layers' GEMMs (per 64-row node tile):
//   phase 1: acc = [AggBf||XBf] @ W1T^T ; h_tile = bf16(relu(acc + b1)) -> LDS
//   phase 2: [t2_bf | u] = h_tile @ WT2^T
// Staging via global_load_lds width=16 (direct to LDS, no VGPR round-trip);
// source addresses pre-swizzled so the (unchanged) swizzled ds_reads match.
// BM=64, BK=32, 4 waves. LDS: As 4KB + Bs 16KB + Hs 32KB = 52KB (3 blocks/CU).
__global__ __launch_bounds__(256) void gemm12_fused(
        const unsigned short* __restrict__ AggBf,  // [M,128] bf16
        const unsigned short* __restrict__ XBf,    // [M,128] bf16
        const unsigned short* __restrict__ W1T,    // [256n][256k] bf16
        const float* __restrict__ b1,              // [256]
        const unsigned short* __restrict__ WT2,    // [128n][256k] bf16
        unsigned short* __restrict__ t2bf,         // [M,64] bf16
        float* __restrict__ u,                     // [M,64] f32
        int M)
{
    __shared__ __align__(16) unsigned short As[64 * 32];    // 4 KB
    __shared__ __align__(16) unsigned short Bs[256 * 32];   // 16 KB (reused phase 2)
    __shared__ __align__(16) unsigned short Hs[64 * 256];   // 32 KB h-tile

    const int tid  = threadIdx.x;
    const int wave = tid >> 6, lane = tid & 63;
    const int m0 = blockIdx.x * 64;

    // GLL A-mapping: lane l of wave w fills LDS row a_row = 16w + (l>>2),
    // 16B slot (l&3); source k-block pre-swizzled.
    const int a_row  = (wave << 4) + (lane >> 2);
    int gmA = m0 + a_row; if (gmA >= M) gmA = M - 1;       // clamp (stores masked)
    const int a_kbsrc = (lane & 3) ^ ((a_row >> 1) & 3);

    const int kb = lane >> 4;            // k-block 0..3 (frag reads)
    const int lr = lane & 15;

    // ================= phase 1: h-tile = relu([Agg||X] @ W1T^T + b1) =========
    f32x4 acc[4][4];
    #pragma unroll
    for (int m = 0; m < 4; ++m)
        #pragma unroll
        for (int n = 0; n < 4; ++n) acc[m][n] = (f32x4){0.f, 0.f, 0.f, 0.f};

    for (int k0 = 0; k0 < 256; k0 += 32) {
        {   // stage A (64x32): one GLL per wave
            const unsigned short* srcp = (k0 < 128)
                ? (AggBf + (size_t)gmA * 128 + k0 + a_kbsrc * 8)
                : (XBf   + (size_t)gmA * 128 + (k0 - 128) + a_kbsrc * 8);
            gll16(srcp, (char*)As + (wave << 10));
        }
        #pragma unroll
        for (int i = 0; i < 4; ++i) {   // stage B (256x32): four GLLs per wave
            const int brow  = (i << 6) + (wave << 4) + (lane >> 2);
            const int kbsrc = (lane & 3) ^ ((brow >> 1) & 3);
            gll16(W1T + (size_t)brow * 256 + k0 + kbsrc * 8,
                  (char*)Bs + (i << 12) + (wave << 10));
        }
        __syncthreads();   // drains vmcnt(0): all GLLs complete

        bf16x8 af[4], bfr[4];
        #pragma unroll
        for (int m = 0; m < 4; ++m)
            af[m] = *reinterpret_cast<const bf16x8*>((const char*)As + swz(m * 16 + lr, kb * 16));
        #pragma unroll
        for (int n = 0; n < 4; ++n)
            bfr[n] = *reinterpret_cast<const bf16x8*>(
                (const char*)Bs + swz(wave * 64 + n * 16 + lr, kb * 16));
        #pragma unroll
        for (int m = 0; m < 4; ++m)
            #pragma unroll
            for (int n = 0; n < 4; ++n)
                acc[m][n] = __builtin_amdgcn_mfma_f32_16x16x32_bf16(af[m], bfr[n], acc[m][n], 0, 0, 0);
        __syncthreads();
    }

    // h-tile epilogue into LDS: bias + relu + bf16 (identical math to r13)
    #pragma unroll
    for (int m = 0; m < 4; ++m) {
        const int lrow_base = m * 16 + (lane >> 4) * 4;
        #pragma unroll
        for (int n = 0; n < 4; ++n) {
            const int lcol = wave * 64 + n * 16 + (lane & 15);
            const float b = b1[lcol];
            #pragma unroll
            for (int r = 0; r < 4; ++r) {
                const int lrow = lrow_base + r;
                float v = acc[m][n][r] + b;
                *reinterpret_cast<unsigned short*>((char*)Hs + hswz(lrow, lcol * 2)) =
                    f2bf(fmaxf(v, 0.0f));
            }
        }
    }
    __syncthreads();

    // ================= phase 2: [t2|u] = h_tile @ WT2^T ======================
    f32x4 acc2[4][2];
    #pragma unroll
    for (int m = 0; m < 4; ++m)
        #pragma unroll
        for (int n = 0; n < 2; ++n) acc2[m][n] = (f32x4){0.f, 0.f, 0.f, 0.f};

    for (int k0 = 0; k0 < 256; k0 += 32) {
        #pragma unroll
        for (int i = 0; i < 2; ++i) {   // stage B2 (128x32): two GLLs per wave
            const int brow  = (i << 6) + (wave << 4) + (lane >> 2);
            const int kbsrc = (lane & 3) ^ ((brow >> 1) & 3);
            gll16(WT2 + (size_t)brow * 256 + k0 + kbsrc * 8,
                  (char*)Bs + (i << 12) + (wave << 10));
        }
        __syncthreads();

        bf16x8 af[4], bfr[2];
        #pragma unroll
        for (int m = 0; m < 4; ++m) {
            const int lrow = m * 16 + lr;
            af[m] = *reinterpret_cast<const bf16x8*>(
                (const char*)Hs + hswz(lrow, k0 * 2 + kb * 16));
        }
        #pragma unroll
        for (int n = 0; n < 2; ++n)
            bfr[n] = *reinterpret_cast<const bf16x8*>(
                (const char*)Bs + swz(wave * 32 + n * 16 + lr, kb * 16));
        #pragma unroll
        for (int m = 0; m < 4; ++m)
            #pragma unroll
            for (int n = 0; n < 2; ++n)
                acc2[m][n] = __builtin_amdgcn_mfma_f32_16x16x32_bf16(af[m], bfr[n], acc2[m][n], 0, 0, 0);
        __syncthreads();
    }

    // epilogue: cols 0..63 -> t2 (bf16), 64..127 -> u (f32); mask gr<M
    #pragma unroll
    for (int m = 0; m < 4; ++m) {
        const int gr_base = m0 + m * 16 + (lane >> 4) * 4;
        #pragma unroll
        for (int n = 0; n < 2; ++n) {
            const int gc = wave * 32 + n * 16 + (lane & 15);   // 0..127
            #pragma unroll
            for (int r = 0; r < 4; ++r) {
                const int gr = gr_base + r;
                if (gr < M) {
                    if (gc < 64) t2bf[(size_t)gr * 64 + gc] = f2bf(acc2[m][n][r]);
                    else         u[(size_t)gr * 64 + (gc - 64)] = acc2[m][n][r];
                }
            }
        }
    }
}

// ---------------------------------------------------------------------------
extern "C" void kernel_launch(void* const* d_in, const int* in_sizes, int n_in,
                              void* d_out, int out_size, void* d_ws, size_t ws_size,
                              hipStream_t stream) {
    const float* x    = (const float*)d_in[0];
    const int*   eidx = (const int*)d_in[1];
    const float* W1l  = (const float*)d_in[2];
    const float* b1   = (const float*)d_in[3];
    const float* W1r  = (const float*)d_in[4];
    const float* W2l  = (const float*)d_in[5];
    const float* b2   = (const float*)d_in[6];
    const float* W2r  = (const float*)d_in[7];
    float* out = (float*)d_out;

    const int* src = eidx;
    const int* dst = eidx + E_EDGES;
    const int N = N_NODES, E = E_EDGES;
    const int NSCAN = (N + 2047) / 2048;                 // 49 blocks

    // Workspace layout (~93 MB):
    //   ints:  deg[N] | row_start[N+1] | cursor[N] | nbr[E] | bsums[64]
    //   bf16:  W1T[256*256] | WT2[128*256] | x_bf[N*128] | agg_bf[N*128] | t2_bf[N*64]
    //   f32:   u[N*64]
    int*   deg_i     = (int*)d_ws;
    int*   row_start = deg_i + N;
    int*   cursor    = row_start + (N + 1);
    int*   nbr       = cursor + N;
    int*   bsums     = nbr + E;                          // 64
    char*  fb        = (char*)(((size_t)(bsums + 64) + 15) & ~(size_t)15);
    unsigned short* W1T    = (unsigned short*)fb;               // 256*256
    unsigned short* WT2    = W1T + 256 * 256;                   // 128*256
    unsigned short* x_bf   = WT2 + 128 * 256;                   // N*128
    unsigned short* agg_bf = x_bf + (size_t)N * C_IN;           // N*128
    unsigned short* t2bf   = agg_bf + (size_t)N * C_IN;         // N*64
    float* u = (float*)(((size_t)(t2bf + (size_t)N * C_OUT) + 15) & ~(size_t)15);  // N*64

    // ---- input conversion (independent of CSR) ----
    cvt_x_kernel<<<(N * C_IN / 8 + 255) / 256, 256, 0, stream>>>(x, x_bf, N * C_IN / 8);
    w1T_kernel<<<256, 256, 0, stream>>>(W1l, W1r, W1T);
    w2T_kernel<<<128, 256, 0, stream>>>(W2l, W2r, WT2);

    // ---- CSR build (shared by both layers) ----
    hipMemsetAsync(deg_i, 0, (size_t)N * sizeof(int), stream);
    hist_kernel<<<(E + 255) / 256, 256, 0, stream>>>(dst, deg_i, E);
    scan_partial<<<NSCAN, 256, 0, stream>>>(deg_i, bsums, N);
    scan_bsums<<<1, 64, 0, stream>>>(bsums, NSCAN);
    scan_apply<<<NSCAN, 256, 0, stream>>>(deg_i, bsums, row_start, cursor, N, E);
    fill_kernel<<<(E + 255) / 256, 256, 0, stream>>>(src, dst, cursor, nbr, E);

    // ---- layer 1 aggregation ----
    gather_mean_bf16<<<((size_t)N * 16 + 255) / 256, 256, 0, stream>>>(
        row_start, nbr, x_bf, agg_bf, N);

    // ---- fused GEMMs: h-tile in LDS; [t2_bf|u] out ----
    gemm12_fused<<<(N + 63) / 64, 256, 0, stream>>>(
        agg_bf, x_bf, W1T, b1, WT2, t2bf, u, N);

    // ---- final: out = mean_nbr(t2_bf) + u + b2 ----
    gather_out_kernel<<<((size_t)N * 8 + 255) / 256, 256, 0, stream>>>(
        row_start, nbr, t2bf, u, b2, out, N);
}